// Round 2
// baseline (12523.354 us; speedup 1.0000x reference)
//
#include <hip/hip_runtime.h>
#include <math.h>

// ---------- helpers ----------
__device__ __forceinline__ unsigned encf(float f) {
    unsigned u = __float_as_uint(f);
    return (u & 0x80000000u) ? ~u : (u | 0x80000000u);
}
__device__ __forceinline__ float decf(unsigned u) {
    u = (u & 0x80000000u) ? (u & 0x7FFFFFFFu) : ~u;
    return __uint_as_float(u);
}

// ---------- fp32 tiled GEMM: C[M,Nc] = A[M,K] @ B[K,Nc] (+bias) (+elu) ----------
// 64x64 tile, 256 threads, 4x4 per thread, K-tile 16.
__global__ __launch_bounds__(256) void gemm_kernel(
    const float* __restrict__ A, const float* __restrict__ B,
    const float* __restrict__ bias, float* __restrict__ C,
    int M, int K, int Nc, int act)
{
    __shared__ float As[16][65];
    __shared__ float Bs[16][64];
    int tid = threadIdx.x;
    int tx = tid & 15, ty = tid >> 4;
    int row0 = blockIdx.y * 64;
    int col0 = blockIdx.x * 64;
    float acc[4][4] = {};

    for (int k0 = 0; k0 < K; k0 += 16) {
        #pragma unroll
        for (int i = 0; i < 4; i++) {
            int idx = tid + i * 256;
            int r = idx >> 4, c = idx & 15;
            int gr = row0 + r;
            As[c][r] = (gr < M) ? A[(size_t)gr * K + k0 + c] : 0.f;
        }
        #pragma unroll
        for (int i = 0; i < 4; i++) {
            int idx = tid + i * 256;
            int r = idx >> 6, c = idx & 63;
            Bs[r][c] = B[(size_t)(k0 + r) * Nc + col0 + c];
        }
        __syncthreads();
        #pragma unroll
        for (int kk = 0; kk < 16; kk++) {
            float a[4], b[4];
            #pragma unroll
            for (int i = 0; i < 4; i++) a[i] = As[kk][ty * 4 + i];
            #pragma unroll
            for (int j = 0; j < 4; j++) b[j] = Bs[kk][tx * 4 + j];
            #pragma unroll
            for (int i = 0; i < 4; i++)
                #pragma unroll
                for (int j = 0; j < 4; j++)
                    acc[i][j] = fmaf(a[i], b[j], acc[i][j]);
        }
        __syncthreads();
    }
    #pragma unroll
    for (int i = 0; i < 4; i++) {
        int gr = row0 + ty * 4 + i;
        if (gr >= M) continue;
        #pragma unroll
        for (int j = 0; j < 4; j++) {
            int gc = col0 + tx * 4 + j;
            float v = acc[i][j];
            if (bias) v += bias[gc];
            if (act == 1) v = v > 0.f ? v : (expf(v) - 1.f);  // elu
            C[(size_t)gr * Nc + gc] = v;
        }
    }
}

// ---------- per-(node,head) attention scores: es = h.a_src, ed = h.a_dst ----------
__global__ __launch_bounds__(256) void attn_scores_kernel(
    const float* __restrict__ h, const float* __restrict__ asrc, const float* __restrict__ adst,
    float* __restrict__ es, float* __restrict__ ed, int Nn, int H, int C)
{
    int wid = (blockIdx.x * 256 + threadIdx.x) >> 6;
    int lane = threadIdx.x & 63;
    if (wid >= Nn * H) return;
    int node = wid / H, hh = wid % H;
    const float* hp = h + (size_t)node * H * C + hh * C;
    float ss = 0.f, sd = 0.f;
    for (int c = lane; c < C; c += 64) {
        float v = hp[c];
        ss = fmaf(v, asrc[hh * C + c], ss);
        sd = fmaf(v, adst[hh * C + c], sd);
    }
    #pragma unroll
    for (int o = 32; o; o >>= 1) { ss += __shfl_down(ss, o); sd += __shfl_down(sd, o); }
    if (lane == 0) { es[wid] = ss; ed[wid] = sd; }
}

// ---------- edge pass A: leaky-relu logits + segment max (encoded atomicMax) ----------
__global__ __launch_bounds__(256) void edge_pass_a(
    const int* __restrict__ ei, const float* __restrict__ es, const float* __restrict__ ed,
    float* __restrict__ wsl, unsigned* __restrict__ menc, int E, int Nn, int H)
{
    int tid = blockIdx.x * 256 + threadIdx.x;
    int tot = (E + Nn) * H;
    if (tid >= tot) return;
    int e = tid / H, hh = tid - e * H;
    int s, d;
    if (e < E) { s = ei[e]; d = ei[E + e]; } else { s = d = e - E; }
    float l = es[s * H + hh] + ed[d * H + hh];
    l = l > 0.f ? l : 0.2f * l;                 // leaky_relu(0.2)
    wsl[tid] = l;
    atomicMax(&menc[d * H + hh], encf(l));
}

// ---------- edge pass B: exp(logit - max), accumulate denominator ----------
__global__ __launch_bounds__(256) void edge_pass_b(
    const int* __restrict__ ei, float* __restrict__ wsl,
    const unsigned* __restrict__ menc, float* __restrict__ den, int E, int Nn, int H)
{
    int tid = blockIdx.x * 256 + threadIdx.x;
    int tot = (E + Nn) * H;
    if (tid >= tot) return;
    int e = tid / H, hh = tid - e * H;
    int d;
    if (e < E) { d = ei[E + e]; } else { d = e - E; }
    float m = decf(menc[d * H + hh]);
    float ex = expf(wsl[tid] - m);
    wsl[tid] = ex;
    atomicAdd(&den[d * H + hh], ex);
}

// ---------- edge pass C: agg[dst] += alpha * h[src], one wave per edge ----------
__global__ __launch_bounds__(256) void edge_scatter(
    const int* __restrict__ ei, const float* __restrict__ wse, const float* __restrict__ den,
    const float* __restrict__ h, float* __restrict__ agg, int E, int Nn, int H, int C)
{
    int wid = (blockIdx.x * 256 + threadIdx.x) >> 6;
    int lane = threadIdx.x & 63;
    int Etot = E + Nn;
    if (wid >= Etot) return;
    int s, d;
    if (wid < E) { s = ei[wid]; d = ei[E + wid]; } else { s = d = wid - E; }
    int HC = H * C;
    const float4* hp = (const float4*)(h + (size_t)s * HC);
    float* ap = agg + (size_t)d * HC;
    int n4 = HC >> 2;
    for (int i = lane; i < n4; i += 64) {
        int head = (i << 2) / C;
        float al = wse[(size_t)wid * H + head] / (den[(size_t)d * H + head] + 1e-16f);
        float4 v = hp[i];
        int c = i << 2;
        atomicAdd(ap + c + 0, al * v.x);
        atomicAdd(ap + c + 1, al * v.y);
        atomicAdd(ap + c + 2, al * v.z);
        atomicAdd(ap + c + 3, al * v.w);
    }
}

// ---------- bias + layernorm + elu (+residual) ----------
// NOTE: `out` may alias `agg` or `resid` row-for-row: all global reads of the
// row happen before the first __syncthreads(); writes happen after the last.
__global__ __launch_bounds__(256) void ln_elu_kernel(
    const float* __restrict__ agg, const float* __restrict__ bias,
    const float* __restrict__ gam, const float* __restrict__ bet,
    const float* __restrict__ resid, float* __restrict__ out, int HC)
{
    int row = blockIdx.x;
    int tid = threadIdx.x;
    int per = HC >> 8;          // 4 for 1024, 1 for 256
    float vr[4];
    const float* ap = agg + (size_t)row * HC;
    float sum = 0.f;
    for (int i = 0; i < per; i++) {
        int c = i * 256 + tid;
        float x = ap[c] + bias[c];
        vr[i] = x; sum += x;
    }
    __shared__ float sm[4];
    #pragma unroll
    for (int o = 32; o; o >>= 1) sum += __shfl_down(sum, o);
    if ((tid & 63) == 0) sm[tid >> 6] = sum;
    __syncthreads();
    float mean = (sm[0] + sm[1] + sm[2] + sm[3]) / (float)HC;
    float sq = 0.f;
    for (int i = 0; i < per; i++) { float dd = vr[i] - mean; sq = fmaf(dd, dd, sq); }
    __syncthreads();
    #pragma unroll
    for (int o = 32; o; o >>= 1) sq += __shfl_down(sq, o);
    if ((tid & 63) == 0) sm[tid >> 6] = sq;
    __syncthreads();
    float var = (sm[0] + sm[1] + sm[2] + sm[3]) / (float)HC;
    float rstd = rsqrtf(var + 1e-5f);
    for (int i = 0; i < per; i++) {
        int c = i * 256 + tid;
        float y = (vr[i] - mean) * rstd * gam[c] + bet[c];
        y = y > 0.f ? y : (expf(y) - 1.f);      // elu
        if (resid) y += resid[(size_t)row * HC + c];
        out[(size_t)row * HC + c] = y;
    }
}

// ---------- graph pooling: sum + max (+count) per graph ----------
__global__ __launch_bounds__(256) void pool_kernel(
    const float* __restrict__ x3, const int* __restrict__ batch,
    float* __restrict__ ps, unsigned* __restrict__ pm, int* __restrict__ cnt, int Nn)
{
    int node = blockIdx.x;
    int c = threadIdx.x;   // 256 channels
    if (node >= Nn) return;
    int g = batch[node];
    float v = x3[(size_t)node * 256 + c];
    atomicAdd(&ps[g * 256 + c], v);
    atomicMax(&pm[g * 256 + c], encf(v));
    if (c == 0) atomicAdd(&cnt[g], 1);
}

// ---------- classifier: [mean|max|sum] @ W1 -> relu -> @ W2 ----------
__global__ __launch_bounds__(128) void classifier_kernel(
    const float* __restrict__ ps, const unsigned* __restrict__ pm, const int* __restrict__ cnt,
    const float* __restrict__ w1, const float* __restrict__ b1,
    const float* __restrict__ w2, const float* __restrict__ b2, float* __restrict__ out)
{
    int g = blockIdx.x;
    int tid = threadIdx.x; // 128
    __shared__ float pooled[768];
    __shared__ float red[2];
    float c = (float)cnt[g];
    if (c < 1.f) c = 1.f;
    for (int i = tid; i < 256; i += 128) {
        float s = ps[g * 256 + i];
        pooled[i] = s / c;
        pooled[256 + i] = decf(pm[g * 256 + i]);
        pooled[512 + i] = s;
    }
    __syncthreads();
    float acc = b1[tid];
    for (int k = 0; k < 768; k++) acc = fmaf(pooled[k], w1[k * 128 + tid], acc);
    acc = fmaxf(acc, 0.f);
    float v = acc * w2[tid];
    #pragma unroll
    for (int o = 32; o; o >>= 1) v += __shfl_down(v, o);
    if ((tid & 63) == 0) red[tid >> 6] = v;
    __syncthreads();
    if (tid == 0) out[g] = red[0] + red[1] + b2[0];
}

// ---------- launcher ----------
extern "C" void kernel_launch(void* const* d_in, const int* in_sizes, int n_in,
                              void* d_out, int out_size, void* d_ws, size_t ws_size,
                              hipStream_t stream)
{
    const float* x      = (const float*)d_in[0];
    const int*   ei     = (const int*)d_in[1];
    const int*   batch  = (const int*)d_in[2];
    const float* proj_w = (const float*)d_in[3];
    const float* proj_b = (const float*)d_in[4];
    const float* gat1_w = (const float*)d_in[5];
    const float* att1_s = (const float*)d_in[6];
    const float* att1_d = (const float*)d_in[7];
    const float* gat1_b = (const float*)d_in[8];
    const float* ln1_g  = (const float*)d_in[9];
    const float* ln1_b  = (const float*)d_in[10];
    const float* gat2_w = (const float*)d_in[11];
    const float* att2_s = (const float*)d_in[12];
    const float* att2_d = (const float*)d_in[13];
    const float* gat2_b = (const float*)d_in[14];
    const float* ln2_g  = (const float*)d_in[15];
    const float* ln2_b  = (const float*)d_in[16];
    const float* gat3_w = (const float*)d_in[17];
    const float* att3_s = (const float*)d_in[18];
    const float* att3_d = (const float*)d_in[19];
    const float* gat3_b = (const float*)d_in[20];
    const float* ln3_g  = (const float*)d_in[21];
    const float* ln3_b  = (const float*)d_in[22];
    const float* cls1_w = (const float*)d_in[23];
    const float* cls1_b = (const float*)d_in[24];
    const float* cls2_w = (const float*)d_in[25];
    const float* cls2_b = (const float*)d_in[26];

    int Nn = in_sizes[0] / 768;
    int E  = in_sizes[1] / 2;
    int Gg = out_size;           // 32
    int Etot = E + Nn;

    // ---- workspace layout: 3 big buffers + small scratch (~252.5 MB) ----
    char* w = (char*)d_ws;
    size_t NB = (size_t)Nn * 1024 * sizeof(float);
    float* bufH   = (float*)(w + 0 * NB);   // h1/h2/h3; x3 written here in L3
    float* bufAgg = (float*)(w + 1 * NB);   // agg each layer (zeroed per layer)
    float* bufX   = (float*)(w + 2 * NB);   // hproj -> x1 -> x2 (in-place resid)
    char* p = w + 3 * NB;
    float*    es   = (float*)p;    p += (size_t)Nn * 4 * 4;
    float*    ed_  = (float*)p;    p += (size_t)Nn * 4 * 4;
    unsigned* menc = (unsigned*)p; p += (size_t)Nn * 4 * 4;
    float*    den  = (float*)p;    p += (size_t)Nn * 4 * 4;
    float*    wsl  = (float*)p;    p += (size_t)Etot * 4 * 4;
    float*    ps   = (float*)p;    p += (size_t)Gg * 256 * 4;
    unsigned* pm   = (unsigned*)p; p += (size_t)Gg * 256 * 4;
    int*      cnt  = (int*)p;      p += 256;

    dim3 blk(256);

    // proj: hproj = elu(x @ proj_w + proj_b)  -> bufX
    {
        dim3 g(768 / 64, (Nn + 63) / 64);
        gemm_kernel<<<g, blk, 0, stream>>>(x, proj_w, proj_b, bufX, Nn, 768, 768, 1);
    }

    auto run_gat = [&](const float* xin, const float* Wm, const float* as_, const float* ad_,
                       const float* gb, const float* lg, const float* lb, const float* resid,
                       float* hbuf, float* aggbuf, float* xout, int K, int H, int C) {
        int HC = H * C;
        dim3 gg(HC / 64, (Nn + 63) / 64);
        gemm_kernel<<<gg, blk, 0, stream>>>(xin, Wm, nullptr, hbuf, Nn, K, HC, 0);
        int nw = Nn * H;
        attn_scores_kernel<<<dim3((nw + 3) / 4), blk, 0, stream>>>(hbuf, as_, ad_, es, ed_, Nn, H, C);
        hipMemsetAsync(menc, 0, (size_t)Nn * H * 4, stream);
        hipMemsetAsync(den, 0, (size_t)Nn * H * 4, stream);
        hipMemsetAsync(aggbuf, 0, (size_t)Nn * HC * 4, stream);
        int tot = Etot * H;
        edge_pass_a<<<dim3((tot + 255) / 256), blk, 0, stream>>>(ei, es, ed_, wsl, menc, E, Nn, H);
        edge_pass_b<<<dim3((tot + 255) / 256), blk, 0, stream>>>(ei, wsl, menc, den, E, Nn, H);
        edge_scatter<<<dim3((Etot + 3) / 4), blk, 0, stream>>>(ei, wsl, den, hbuf, aggbuf, E, Nn, H, C);
        ln_elu_kernel<<<dim3(Nn), blk, 0, stream>>>(aggbuf, gb, lg, lb, resid, xout, HC);
    };

    // layer 1: 768 -> 4x256 concat.  x1 -> bufX (hproj dead after h1 GEMM)
    run_gat(bufX, gat1_w, att1_s, att1_d, gat1_b, ln1_g, ln1_b, nullptr, bufH, bufAgg, bufX, 768, 4, 256);
    // layer 2: 1024 -> 4x256 concat, +x1 residual, written IN PLACE into bufX
    run_gat(bufX, gat2_w, att2_s, att2_d, gat2_b, ln2_g, ln2_b, bufX,   bufH, bufAgg, bufX, 1024, 4, 256);
    // layer 3: 1024 -> 1x256 (mean over 1 head = identity). x3 -> bufH (h3 dead)
    run_gat(bufX, gat3_w, att3_s, att3_d, gat3_b, ln3_g, ln3_b, nullptr, bufH, bufAgg, bufH, 1024, 1, 256);

    // pooling + classifier
    hipMemsetAsync(ps, 0, (size_t)Gg * 256 * 4, stream);
    hipMemsetAsync(pm, 0, (size_t)Gg * 256 * 4, stream);
    hipMemsetAsync(cnt, 0, (size_t)Gg * 4, stream);
    pool_kernel<<<dim3(Nn), blk, 0, stream>>>(bufH, batch, ps, pm, cnt, Nn);
    classifier_kernel<<<dim3(Gg), dim3(128), 0, stream>>>(ps, pm, cnt, cls1_w, cls1_b, cls2_w, cls2_b, (float*)d_out);
}

// Round 3
// 2691.412 us; speedup vs baseline: 4.6531x; 4.6531x over previous
//
#include <hip/hip_runtime.h>
#include <math.h>

// ---------- helpers ----------
__device__ __forceinline__ unsigned encf(float f) {
    unsigned u = __float_as_uint(f);
    return (u & 0x80000000u) ? ~u : (u | 0x80000000u);
}
__device__ __forceinline__ float decf(unsigned u) {
    u = (u & 0x80000000u) ? (u & 0x7FFFFFFFu) : ~u;
    return __uint_as_float(u);
}

// ---------- fp32 tiled GEMM: C[M,Nc] = A[M,K] @ B[K,Nc] (+bias) (+elu) ----------
__global__ __launch_bounds__(256) void gemm_kernel(
    const float* __restrict__ A, const float* __restrict__ B,
    const float* __restrict__ bias, float* __restrict__ C,
    int M, int K, int Nc, int act)
{
    __shared__ float As[16][65];
    __shared__ float Bs[16][64];
    int tid = threadIdx.x;
    int tx = tid & 15, ty = tid >> 4;
    int row0 = blockIdx.y * 64;
    int col0 = blockIdx.x * 64;
    float acc[4][4] = {};

    for (int k0 = 0; k0 < K; k0 += 16) {
        #pragma unroll
        for (int i = 0; i < 4; i++) {
            int idx = tid + i * 256;
            int r = idx >> 4, c = idx & 15;
            int gr = row0 + r;
            As[c][r] = (gr < M) ? A[(size_t)gr * K + k0 + c] : 0.f;
        }
        #pragma unroll
        for (int i = 0; i < 4; i++) {
            int idx = tid + i * 256;
            int r = idx >> 6, c = idx & 63;
            Bs[r][c] = B[(size_t)(k0 + r) * Nc + col0 + c];
        }
        __syncthreads();
        #pragma unroll
        for (int kk = 0; kk < 16; kk++) {
            float a[4], b[4];
            #pragma unroll
            for (int i = 0; i < 4; i++) a[i] = As[kk][ty * 4 + i];
            #pragma unroll
            for (int j = 0; j < 4; j++) b[j] = Bs[kk][tx * 4 + j];
            #pragma unroll
            for (int i = 0; i < 4; i++)
                #pragma unroll
                for (int j = 0; j < 4; j++)
                    acc[i][j] = fmaf(a[i], b[j], acc[i][j]);
        }
        __syncthreads();
    }
    #pragma unroll
    for (int i = 0; i < 4; i++) {
        int gr = row0 + ty * 4 + i;
        if (gr >= M) continue;
        #pragma unroll
        for (int j = 0; j < 4; j++) {
            int gc = col0 + tx * 4 + j;
            float v = acc[i][j];
            if (bias) v += bias[gc];
            if (act == 1) v = v > 0.f ? v : (expf(v) - 1.f);  // elu
            C[(size_t)gr * Nc + gc] = v;
        }
    }
}

// ---------- per-(node,head) attention scores: es = h.a_src, ed = h.a_dst ----------
__global__ __launch_bounds__(256) void attn_scores_kernel(
    const float* __restrict__ h, const float* __restrict__ asrc, const float* __restrict__ adst,
    float* __restrict__ es, float* __restrict__ ed, int Nn, int H, int C)
{
    int wid = (blockIdx.x * 256 + threadIdx.x) >> 6;
    int lane = threadIdx.x & 63;
    if (wid >= Nn * H) return;
    int node = wid / H, hh = wid % H;
    const float* hp = h + (size_t)node * H * C + hh * C;
    float ss = 0.f, sd = 0.f;
    for (int c = lane; c < C; c += 64) {
        float v = hp[c];
        ss = fmaf(v, asrc[hh * C + c], ss);
        sd = fmaf(v, adst[hh * C + c], sd);
    }
    #pragma unroll
    for (int o = 32; o; o >>= 1) { ss += __shfl_down(ss, o); sd += __shfl_down(sd, o); }
    if (lane == 0) { es[wid] = ss; ed[wid] = sd; }
}

// ---------- CSR build ----------
__global__ __launch_bounds__(256) void csr_init(int* __restrict__ deg, int Nn) {
    int i = blockIdx.x * 256 + threadIdx.x;
    if (i < Nn) deg[i] = 1;               // self-loop
}
__global__ __launch_bounds__(256) void csr_count(const int* __restrict__ ei, int* __restrict__ deg, int E) {
    int i = blockIdx.x * 256 + threadIdx.x;
    if (i < E) atomicAdd(&deg[ei[E + i]], 1);
}
// inclusive block-scan (256/block) -> incl, block totals -> bsums
__global__ __launch_bounds__(256) void scan1(const int* __restrict__ deg, int* __restrict__ incl,
                                             int* __restrict__ bsums, int Nn) {
    __shared__ int sd[256];
    int idx = blockIdx.x * 256 + threadIdx.x;
    sd[threadIdx.x] = (idx < Nn) ? deg[idx] : 0;
    __syncthreads();
    for (int o = 1; o < 256; o <<= 1) {
        int x = (threadIdx.x >= (unsigned)o) ? sd[threadIdx.x - o] : 0;
        __syncthreads();
        sd[threadIdx.x] += x;
        __syncthreads();
    }
    if (idx < Nn) incl[idx] = sd[threadIdx.x];
    if (threadIdx.x == 255) bsums[blockIdx.x] = sd[255];
}
// exclusive scan of block sums (nb ~ 79, serial is fine: once per call)
__global__ void scan2(int* __restrict__ bsums, int nb) {
    if (blockIdx.x == 0 && threadIdx.x == 0) {
        int run = 0;
        for (int i = 0; i < nb; i++) { int v = bsums[i]; bsums[i] = run; run += v; }
    }
}
__global__ __launch_bounds__(256) void scan3(const int* __restrict__ incl, const int* __restrict__ deg,
                                             const int* __restrict__ bsums, int* __restrict__ rowstart,
                                             int* __restrict__ cursor, int Nn) {
    int idx = blockIdx.x * 256 + threadIdx.x;
    if (idx >= Nn) return;
    int rs = incl[idx] - deg[idx] + bsums[blockIdx.x];
    rowstart[idx] = rs;
    cursor[idx] = rs;
}
__global__ __launch_bounds__(256) void csr_fill(const int* __restrict__ ei, int* __restrict__ cursor,
                                                int* __restrict__ csrc, int E, int Nn) {
    int i = blockIdx.x * 256 + threadIdx.x;
    if (i >= E + Nn) return;
    int s, d;
    if (i < E) { s = ei[i]; d = ei[E + i]; } else { s = d = i - E; }
    int pos = atomicAdd(&cursor[d], 1);
    csrc[pos] = s;
}

// ---------- fused segment-softmax + gather-aggregate ----------
// One block per dst node. C=256 fixed; H in {1,4}. T = 64*H threads; each
// thread owns exactly one float4 of the output row in phase 2.
template<int H>
__global__ __launch_bounds__(64 * H) void gat_aggregate(
    const int* __restrict__ rowstart, const int* __restrict__ deg,
    const int* __restrict__ csrc,
    const float* __restrict__ es, const float* __restrict__ ed,
    const float* __restrict__ h, float* __restrict__ out)
{
    constexpr int T = 64 * H;
    constexpr int NW = T / 64;
    int d = blockIdx.x;
    int t = threadIdx.x;
    int lane = t & 63, wave = t >> 6;
    int head = t & (H - 1);
    int slot = t / H;                      // 64 slots per head
    int st = rowstart[d], dg = deg[d];

    __shared__ float red[NW][H];
    __shared__ float mh[H], zh[H];

    float edv = ed[d * H + head];
    // ---- phase 1a: per-head max of leaky-relu logits ----
    float m = -1e30f;
    for (int j = slot; j < dg; j += 64) {
        int s = csrc[st + j];
        float l = es[s * H + head] + edv;
        l = l > 0.f ? l : 0.2f * l;
        m = fmaxf(m, l);
    }
    #pragma unroll
    for (int o = H; o < 64; o <<= 1) m = fmaxf(m, __shfl_xor(m, o));
    if (NW > 1) {
        if (lane < H) red[wave][head] = m;
        __syncthreads();
        m = red[0][head];
        #pragma unroll
        for (int w2 = 1; w2 < NW; w2++) m = fmaxf(m, red[w2][head]);
        __syncthreads();
    }
    // ---- phase 1b: per-head sum of exp ----
    float z = 0.f;
    for (int j = slot; j < dg; j += 64) {
        int s = csrc[st + j];
        float l = es[s * H + head] + edv;
        l = l > 0.f ? l : 0.2f * l;
        z += expf(l - m);
    }
    #pragma unroll
    for (int o = H; o < 64; o <<= 1) z += __shfl_xor(z, o);
    if (NW > 1) {
        if (lane < H) red[wave][head] = z;
        __syncthreads();
        z = 0.f;
        #pragma unroll
        for (int w2 = 0; w2 < NW; w2++) z += red[w2][head];
    }
    if (t < H) { mh[t] = m; zh[t] = z; }   // t<H => head==t, holds final m,z
    __syncthreads();

    // ---- phase 2: gather alpha*h[src], one float4 per thread ----
    int head2 = t >> 6;                    // (t*4)/C with C=256
    float m2 = mh[head2];
    float rden = 1.f / (zh[head2] + 1e-16f);
    float ed2 = ed[d * H + head2];
    const float4* h4 = (const float4*)h;
    float4 acc = make_float4(0.f, 0.f, 0.f, 0.f);
    for (int j = 0; j < dg; j++) {
        int s = csrc[st + j];
        float l = es[s * H + head2] + ed2;
        l = l > 0.f ? l : 0.2f * l;
        float a = expf(l - m2) * rden;
        float4 v = h4[(size_t)s * T + t];  // s*(HC/4) + t
        acc.x = fmaf(a, v.x, acc.x);
        acc.y = fmaf(a, v.y, acc.y);
        acc.z = fmaf(a, v.z, acc.z);
        acc.w = fmaf(a, v.w, acc.w);
    }
    ((float4*)out)[(size_t)d * T + t] = acc;
}

// ---------- bias + layernorm + elu (+residual) ----------
// NOTE: `out` may alias `agg` or `resid` row-for-row (no __restrict__ here on
// purpose): all reads of a row precede its writes within each thread.
__global__ __launch_bounds__(256) void ln_elu_kernel(
    const float* agg, const float* __restrict__ bias,
    const float* __restrict__ gam, const float* __restrict__ bet,
    const float* resid, float* out, int HC)
{
    int row = blockIdx.x;
    int tid = threadIdx.x;
    int per = HC >> 8;          // 4 for 1024, 1 for 256
    float vr[4];
    const float* ap = agg + (size_t)row * HC;
    float sum = 0.f;
    for (int i = 0; i < per; i++) {
        int c = i * 256 + tid;
        float x = ap[c] + bias[c];
        vr[i] = x; sum += x;
    }
    __shared__ float sm[4];
    #pragma unroll
    for (int o = 32; o; o >>= 1) sum += __shfl_down(sum, o);
    if ((tid & 63) == 0) sm[tid >> 6] = sum;
    __syncthreads();
    float mean = (sm[0] + sm[1] + sm[2] + sm[3]) / (float)HC;
    float sq = 0.f;
    for (int i = 0; i < per; i++) { float dd = vr[i] - mean; sq = fmaf(dd, dd, sq); }
    __syncthreads();
    #pragma unroll
    for (int o = 32; o; o >>= 1) sq += __shfl_down(sq, o);
    if ((tid & 63) == 0) sm[tid >> 6] = sq;
    __syncthreads();
    float var = (sm[0] + sm[1] + sm[2] + sm[3]) / (float)HC;
    float rstd = rsqrtf(var + 1e-5f);
    for (int i = 0; i < per; i++) {
        int c = i * 256 + tid;
        float y = (vr[i] - mean) * rstd * gam[c] + bet[c];
        y = y > 0.f ? y : (expf(y) - 1.f);      // elu
        if (resid) y += resid[(size_t)row * HC + c];
        out[(size_t)row * HC + c] = y;
    }
}

// ---------- graph pooling: sum + max (+count) per graph ----------
__global__ __launch_bounds__(256) void pool_kernel(
    const float* __restrict__ x3, const int* __restrict__ batch,
    float* __restrict__ ps, unsigned* __restrict__ pm, int* __restrict__ cnt, int Nn)
{
    int node = blockIdx.x;
    int c = threadIdx.x;   // 256 channels
    if (node >= Nn) return;
    int g = batch[node];
    float v = x3[(size_t)node * 256 + c];
    atomicAdd(&ps[g * 256 + c], v);
    atomicMax(&pm[g * 256 + c], encf(v));
    if (c == 0) atomicAdd(&cnt[g], 1);
}

// ---------- classifier: [mean|max|sum] @ W1 -> relu -> @ W2 ----------
__global__ __launch_bounds__(128) void classifier_kernel(
    const float* __restrict__ ps, const unsigned* __restrict__ pm, const int* __restrict__ cnt,
    const float* __restrict__ w1, const float* __restrict__ b1,
    const float* __restrict__ w2, const float* __restrict__ b2, float* __restrict__ out)
{
    int g = blockIdx.x;
    int tid = threadIdx.x; // 128
    __shared__ float pooled[768];
    __shared__ float red[2];
    float c = (float)cnt[g];
    if (c < 1.f) c = 1.f;
    for (int i = tid; i < 256; i += 128) {
        float s = ps[g * 256 + i];
        pooled[i] = s / c;
        pooled[256 + i] = decf(pm[g * 256 + i]);
        pooled[512 + i] = s;
    }
    __syncthreads();
    float acc = b1[tid];
    for (int k = 0; k < 768; k++) acc = fmaf(pooled[k], w1[k * 128 + tid], acc);
    acc = fmaxf(acc, 0.f);
    float v = acc * w2[tid];
    #pragma unroll
    for (int o = 32; o; o >>= 1) v += __shfl_down(v, o);
    if ((tid & 63) == 0) red[tid >> 6] = v;
    __syncthreads();
    if (tid == 0) out[g] = red[0] + red[1] + b2[0];
}

// ---------- launcher ----------
extern "C" void kernel_launch(void* const* d_in, const int* in_sizes, int n_in,
                              void* d_out, int out_size, void* d_ws, size_t ws_size,
                              hipStream_t stream)
{
    const float* x      = (const float*)d_in[0];
    const int*   ei     = (const int*)d_in[1];
    const int*   batch  = (const int*)d_in[2];
    const float* proj_w = (const float*)d_in[3];
    const float* proj_b = (const float*)d_in[4];
    const float* gat1_w = (const float*)d_in[5];
    const float* att1_s = (const float*)d_in[6];
    const float* att1_d = (const float*)d_in[7];
    const float* gat1_b = (const float*)d_in[8];
    const float* ln1_g  = (const float*)d_in[9];
    const float* ln1_b  = (const float*)d_in[10];
    const float* gat2_w = (const float*)d_in[11];
    const float* att2_s = (const float*)d_in[12];
    const float* att2_d = (const float*)d_in[13];
    const float* gat2_b = (const float*)d_in[14];
    const float* ln2_g  = (const float*)d_in[15];
    const float* ln2_b  = (const float*)d_in[16];
    const float* gat3_w = (const float*)d_in[17];
    const float* att3_s = (const float*)d_in[18];
    const float* att3_d = (const float*)d_in[19];
    const float* gat3_b = (const float*)d_in[20];
    const float* ln3_g  = (const float*)d_in[21];
    const float* ln3_b  = (const float*)d_in[22];
    const float* cls1_w = (const float*)d_in[23];
    const float* cls1_b = (const float*)d_in[24];
    const float* cls2_w = (const float*)d_in[25];
    const float* cls2_b = (const float*)d_in[26];

    int Nn = in_sizes[0] / 768;
    int E  = in_sizes[1] / 2;
    int Gg = out_size;           // 32
    int Etot = E + Nn;
    int nb  = (Nn + 255) / 256;  // scan blocks

    // ---- workspace layout: 3 big buffers + small scratch ----
    char* w = (char*)d_ws;
    size_t NB = (size_t)Nn * 1024 * sizeof(float);
    float* bufH   = (float*)(w + 0 * NB);   // h1/h2/h3; x3 written here in L3
    float* bufAgg = (float*)(w + 1 * NB);   // agg each layer
    float* bufX   = (float*)(w + 2 * NB);   // hproj -> x1 -> x2 (in-place resid)
    char* p = w + 3 * NB;
    float*    es    = (float*)p;  p += (size_t)Nn * 4 * 4;
    float*    ed_   = (float*)p;  p += (size_t)Nn * 4 * 4;
    int*      deg   = (int*)p;    p += (size_t)Nn * 4;
    int*      incl  = (int*)p;    p += (size_t)Nn * 4;
    int*      rowst = (int*)p;    p += (size_t)Nn * 4;
    int*      curs  = (int*)p;    p += (size_t)Nn * 4;
    int*      bsums = (int*)p;    p += (size_t)nb * 4 + 64;
    int*      csrc  = (int*)p;    p += (size_t)Etot * 4;
    float*    ps    = (float*)p;  p += (size_t)Gg * 256 * 4;
    unsigned* pm    = (unsigned*)p; p += (size_t)Gg * 256 * 4;
    int*      cnt   = (int*)p;    p += 256;

    dim3 blk(256);

    // ---- CSR by dst (built once, reused by all 3 layers) ----
    csr_init<<<dim3(nb), blk, 0, stream>>>(deg, Nn);
    csr_count<<<dim3((E + 255) / 256), blk, 0, stream>>>(ei, deg, E);
    scan1<<<dim3(nb), blk, 0, stream>>>(deg, incl, bsums, Nn);
    scan2<<<dim3(1), dim3(64), 0, stream>>>(bsums, nb);
    scan3<<<dim3(nb), blk, 0, stream>>>(incl, deg, bsums, rowst, curs, Nn);
    csr_fill<<<dim3((Etot + 255) / 256), blk, 0, stream>>>(ei, curs, csrc, E, Nn);

    // proj: hproj = elu(x @ proj_w + proj_b)  -> bufX
    {
        dim3 g(768 / 64, (Nn + 63) / 64);
        gemm_kernel<<<g, blk, 0, stream>>>(x, proj_w, proj_b, bufX, Nn, 768, 768, 1);
    }

    auto run_gat = [&](const float* xin, const float* Wm, const float* as_, const float* ad_,
                       const float* gb, const float* lg, const float* lb, const float* resid,
                       float* hbuf, float* aggbuf, float* xout, int K, int H, int C) {
        int HC = H * C;
        dim3 gg(HC / 64, (Nn + 63) / 64);
        gemm_kernel<<<gg, blk, 0, stream>>>(xin, Wm, nullptr, hbuf, Nn, K, HC, 0);
        int nw = Nn * H;
        attn_scores_kernel<<<dim3((nw + 3) / 4), blk, 0, stream>>>(hbuf, as_, ad_, es, ed_, Nn, H, C);
        if (H == 4)
            gat_aggregate<4><<<dim3(Nn), dim3(256), 0, stream>>>(rowst, deg, csrc, es, ed_, hbuf, aggbuf);
        else
            gat_aggregate<1><<<dim3(Nn), dim3(64), 0, stream>>>(rowst, deg, csrc, es, ed_, hbuf, aggbuf);
        ln_elu_kernel<<<dim3(Nn), blk, 0, stream>>>(aggbuf, gb, lg, lb, resid, xout, HC);
    };

    // layer 1: 768 -> 4x256 concat.  x1 -> bufX (hproj dead after h1 GEMM)
    run_gat(bufX, gat1_w, att1_s, att1_d, gat1_b, ln1_g, ln1_b, nullptr, bufH, bufAgg, bufX, 768, 4, 256);
    // layer 2: 1024 -> 4x256 concat, +x1 residual, written IN PLACE into bufX
    run_gat(bufX, gat2_w, att2_s, att2_d, gat2_b, ln2_g, ln2_b, bufX,   bufH, bufAgg, bufX, 1024, 4, 256);
    // layer 3: 1024 -> 1x256 (mean over 1 head = identity). x3 -> bufH (h3 dead)
    run_gat(bufX, gat3_w, att3_s, att3_d, gat3_b, ln3_g, ln3_b, nullptr, bufH, bufAgg, bufH, 1024, 1, 256);

    // pooling + classifier
    hipMemsetAsync(ps, 0, (size_t)Gg * 256 * 4, stream);
    hipMemsetAsync(pm, 0, (size_t)Gg * 256 * 4, stream);
    hipMemsetAsync(cnt, 0, (size_t)Gg * 4, stream);
    pool_kernel<<<dim3(Nn), blk, 0, stream>>>(bufH, batch, ps, pm, cnt, Nn);
    classifier_kernel<<<dim3(Gg), dim3(128), 0, stream>>>(ps, pm, cnt, cls1_w, cls1_b, cls2_w, cls2_b, (float*)d_out);
}

// Round 5
// 942.744 us; speedup vs baseline: 13.2839x; 2.8549x over previous
//
#include <hip/hip_runtime.h>
#include <math.h>

typedef float floatx4 __attribute__((ext_vector_type(4)));
typedef _Float16 f16x8 __attribute__((ext_vector_type(8)));
typedef _Float16 f16x4 __attribute__((ext_vector_type(4)));

// ---------- helpers ----------
__device__ __forceinline__ unsigned encf(float f) {
    unsigned u = __float_as_uint(f);
    return (u & 0x80000000u) ? ~u : (u | 0x80000000u);
}
__device__ __forceinline__ float decf(unsigned u) {
    u = (u & 0x80000000u) ? (u & 0x7FFFFFFFu) : ~u;
    return __uint_as_float(u);
}

// ---------- fp32 -> fp16 convert (vec4) ----------
__global__ __launch_bounds__(256) void cvt_f16_kernel(
    const float* __restrict__ in, _Float16* __restrict__ out, size_t n4)
{
    size_t i = (size_t)blockIdx.x * 256 + threadIdx.x;
    if (i >= n4) return;
    float4 v = ((const float4*)in)[i];
    f16x4 o;
    o[0] = (_Float16)v.x; o[1] = (_Float16)v.y; o[2] = (_Float16)v.z; o[3] = (_Float16)v.w;
    ((f16x4*)out)[i] = o;
}

// ---------- weight transpose + convert: w[K,N] fp32 -> wt[N,K] fp16 ----------
__global__ __launch_bounds__(256) void wt_kernel(
    const float* __restrict__ w, _Float16* __restrict__ wt, int K, int N)
{
    __shared__ float t[32][33];
    int bx = blockIdx.x * 32, by = blockIdx.y * 32;   // bx: n, by: k
    int tx = threadIdx.x & 31, ty = threadIdx.x >> 5; // 32x8
    for (int r = ty; r < 32; r += 8)
        t[r][tx] = w[(size_t)(by + r) * N + bx + tx];
    __syncthreads();
    for (int r = ty; r < 32; r += 8)
        wt[(size_t)(bx + r) * K + by + tx] = (_Float16)t[tx][r];
}

// ---------- fp16 MFMA GEMM: C[M,N] = A[M,K] @ B, BT=[N,K] fp16 ----------
// 128x128 tile, BK=32, 256 threads (4 waves, 2x2 of 64x64), 4x4 16x16 frags.
__global__ __launch_bounds__(256) void gemm_f16(
    const _Float16* __restrict__ A, const _Float16* __restrict__ BT,
    const float* __restrict__ bias, _Float16* __restrict__ C,
    int M, int K, int N, int act)
{
    __shared__ _Float16 Al[128 * 32];
    __shared__ _Float16 Bl[128 * 32];
    int tid = threadIdx.x;
    int lane = tid & 63, wave = tid >> 6;
    int row0 = blockIdx.y * 128, col0 = blockIdx.x * 128;
    int wm = (wave >> 1) * 64, wn = (wave & 1) * 64;
    int l15 = lane & 15, quad = lane >> 4;

    // staging: thread covers (row=tid>>2, chunk=tid&3) and (+64 rows)
    int sr0 = tid >> 2, sc = (tid & 3) * 8;
    int sr1 = sr0 + 64;
    int ar0 = row0 + sr0; if (ar0 > M - 1) ar0 = M - 1;
    int ar1 = row0 + sr1; if (ar1 > M - 1) ar1 = M - 1;
    const _Float16* Ap0 = A + (size_t)ar0 * K + sc;
    const _Float16* Ap1 = A + (size_t)ar1 * K + sc;
    const _Float16* Bp0 = BT + (size_t)(col0 + sr0) * K + sc;
    const _Float16* Bp1 = BT + (size_t)(col0 + sr1) * K + sc;

    floatx4 acc[4][4] = {};

    for (int k0 = 0; k0 < K; k0 += 32) {
        f16x8 a0 = *(const f16x8*)(Ap0 + k0);
        f16x8 a1 = *(const f16x8*)(Ap1 + k0);
        f16x8 b0 = *(const f16x8*)(Bp0 + k0);
        f16x8 b1 = *(const f16x8*)(Bp1 + k0);
        __syncthreads();               // prior iter's ds_reads done
        *(f16x8*)&Al[sr0 * 32 + sc] = a0;
        *(f16x8*)&Al[sr1 * 32 + sc] = a1;
        *(f16x8*)&Bl[sr0 * 32 + sc] = b0;
        *(f16x8*)&Bl[sr1 * 32 + sc] = b1;
        __syncthreads();
        f16x8 af[4], bfr[4];
        #pragma unroll
        for (int i = 0; i < 4; i++) {
            af[i]  = *(const f16x8*)&Al[(wm + i * 16 + l15) * 32 + quad * 8];
            bfr[i] = *(const f16x8*)&Bl[(wn + i * 16 + l15) * 32 + quad * 8];
        }
        #pragma unroll
        for (int i = 0; i < 4; i++)
            #pragma unroll
            for (int j = 0; j < 4; j++)
                acc[i][j] = __builtin_amdgcn_mfma_f32_16x16x32_f16(af[i], bfr[j], acc[i][j], 0, 0, 0);
    }

    // epilogue: D row = quad*4+reg, col = l15 (dtype-independent, m89/m127)
    #pragma unroll
    for (int i = 0; i < 4; i++) {
        #pragma unroll
        for (int v = 0; v < 4; v++) {
            int gr = row0 + wm + i * 16 + quad * 4 + v;
            if (gr >= M) continue;
            #pragma unroll
            for (int j = 0; j < 4; j++) {
                int gc = col0 + wn + j * 16 + l15;
                float val = acc[i][j][v];
                if (bias) val += bias[gc];
                if (act) val = val > 0.f ? val : (expf(val) - 1.f);
                C[(size_t)gr * N + gc] = (_Float16)val;
            }
        }
    }
}

// ---------- per-(node,head) attention scores from fp16 h ----------
__global__ __launch_bounds__(256) void attn_scores_kernel(
    const _Float16* __restrict__ h, const float* __restrict__ asrc, const float* __restrict__ adst,
    float* __restrict__ es, float* __restrict__ ed, int Nn, int H)
{
    int wid = (blockIdx.x * 256 + threadIdx.x) >> 6;
    int lane = threadIdx.x & 63;
    if (wid >= Nn * H) return;
    int node = wid / H, hh = wid % H;
    const _Float16* hp = h + (size_t)node * H * 256 + hh * 256 + lane * 4;
    f16x4 v = *(const f16x4*)hp;
    float ss = 0.f, sd = 0.f;
    #pragma unroll
    for (int j = 0; j < 4; j++) {
        float f = (float)v[j];
        ss = fmaf(f, asrc[hh * 256 + lane * 4 + j], ss);
        sd = fmaf(f, adst[hh * 256 + lane * 4 + j], sd);
    }
    #pragma unroll
    for (int o = 32; o; o >>= 1) { ss += __shfl_down(ss, o); sd += __shfl_down(sd, o); }
    if (lane == 0) { es[wid] = ss; ed[wid] = sd; }
}

// ---------- CSR build ----------
__global__ __launch_bounds__(256) void csr_init(int* __restrict__ deg, int Nn) {
    int i = blockIdx.x * 256 + threadIdx.x;
    if (i < Nn) deg[i] = 1;               // self-loop
}
__global__ __launch_bounds__(256) void csr_count(const int* __restrict__ ei, int* __restrict__ deg, int E) {
    int i = blockIdx.x * 256 + threadIdx.x;
    if (i < E) atomicAdd(&deg[ei[E + i]], 1);
}
__global__ __launch_bounds__(256) void scan1(const int* __restrict__ deg, int* __restrict__ incl,
                                             int* __restrict__ bsums, int Nn) {
    __shared__ int sd[256];
    int idx = blockIdx.x * 256 + threadIdx.x;
    sd[threadIdx.x] = (idx < Nn) ? deg[idx] : 0;
    __syncthreads();
    for (int o = 1; o < 256; o <<= 1) {
        int x = (threadIdx.x >= (unsigned)o) ? sd[threadIdx.x - o] : 0;
        __syncthreads();
        sd[threadIdx.x] += x;
        __syncthreads();
    }
    if (idx < Nn) incl[idx] = sd[threadIdx.x];
    if (threadIdx.x == 255) bsums[blockIdx.x] = sd[255];
}
__global__ void scan2(int* __restrict__ bsums, int nb) {
    if (blockIdx.x == 0 && threadIdx.x == 0) {
        int run = 0;
        for (int i = 0; i < nb; i++) { int v = bsums[i]; bsums[i] = run; run += v; }
    }
}
__global__ __launch_bounds__(256) void scan3(const int* __restrict__ incl, const int* __restrict__ deg,
                                             const int* __restrict__ bsums, int* __restrict__ rowstart,
                                             int* __restrict__ cursor, int Nn) {
    int idx = blockIdx.x * 256 + threadIdx.x;
    if (idx >= Nn) return;
    int rs = incl[idx] - deg[idx] + bsums[blockIdx.x];
    rowstart[idx] = rs;
    cursor[idx] = rs;
}
__global__ __launch_bounds__(256) void csr_fill(const int* __restrict__ ei, int* __restrict__ cursor,
                                                int* __restrict__ csrc, int E, int Nn) {
    int i = blockIdx.x * 256 + threadIdx.x;
    if (i >= E + Nn) return;
    int s, d;
    if (i < E) { s = ei[i]; d = ei[E + i]; } else { s = d = i - E; }
    int pos = atomicAdd(&cursor[d], 1);
    csrc[pos] = s;
}

// ---------- fused segment-softmax + gather-aggregate (fp16 h, fp16 out) ----------
template<int H>
__global__ __launch_bounds__(64 * H) void gat_aggregate(
    const int* __restrict__ rowstart, const int* __restrict__ deg,
    const int* __restrict__ csrc,
    const float* __restrict__ es, const float* __restrict__ ed,
    const _Float16* __restrict__ h, _Float16* __restrict__ out)
{
    constexpr int T = 64 * H;
    constexpr int NW = T / 64;
    int d = blockIdx.x;
    int t = threadIdx.x;
    int lane = t & 63, wave = t >> 6;
    int head = t & (H - 1);
    int slot = t / H;
    int st = rowstart[d], dg = deg[d];

    __shared__ float red[NW][H];
    __shared__ float mh[H], zh[H];

    float edv = ed[d * H + head];
    // phase 1a: per-head max
    float m = -1e30f;
    for (int j = slot; j < dg; j += 64) {
        int s = csrc[st + j];
        float l = es[s * H + head] + edv;
        l = l > 0.f ? l : 0.2f * l;
        m = fmaxf(m, l);
    }
    #pragma unroll
    for (int o = H; o < 64; o <<= 1) m = fmaxf(m, __shfl_xor(m, o));
    if (NW > 1) {
        if (lane < H) red[wave][head] = m;
        __syncthreads();
        m = red[0][head];
        #pragma unroll
        for (int w2 = 1; w2 < NW; w2++) m = fmaxf(m, red[w2][head]);
        __syncthreads();
    }
    // phase 1b: per-head exp-sum
    float z = 0.f;
    for (int j = slot; j < dg; j += 64) {
        int s = csrc[st + j];
        float l = es[s * H + head] + edv;
        l = l > 0.f ? l : 0.2f * l;
        z += expf(l - m);
    }
    #pragma unroll
    for (int o = H; o < 64; o <<= 1) z += __shfl_xor(z, o);
    if (NW > 1) {
        if (lane < H) red[wave][head] = z;
        __syncthreads();
        z = 0.f;
        #pragma unroll
        for (int w2 = 0; w2 < NW; w2++) z += red[w2][head];
    }
    if (t < H) { mh[t] = m; zh[t] = z; }
    __syncthreads();

    // phase 2: gather alpha*h[src]; thread owns 4 fp16 (8 B) of the row
    int head2 = t >> 6;
    float m2 = mh[head2];
    float rden = 1.f / (zh[head2] + 1e-16f);
    float ed2 = ed[d * H + head2];
    float acc0 = 0.f, acc1 = 0.f, acc2 = 0.f, acc3 = 0.f;
    const _Float16* hb = h + (size_t)t * 4;
    int HC = T * 4;
    for (int j = 0; j < dg; j++) {
        int s = csrc[st + j];
        float l = es[s * H + head2] + ed2;
        l = l > 0.f ? l : 0.2f * l;
        float a = expf(l - m2) * rden;
        f16x4 v = *(const f16x4*)(hb + (size_t)s * HC);
        acc0 = fmaf(a, (float)v[0], acc0);
        acc1 = fmaf(a, (float)v[1], acc1);
        acc2 = fmaf(a, (float)v[2], acc2);
        acc3 = fmaf(a, (float)v[3], acc3);
    }
    f16x4 o;
    o[0] = (_Float16)acc0; o[1] = (_Float16)acc1; o[2] = (_Float16)acc2; o[3] = (_Float16)acc3;
    *(f16x4*)(out + (size_t)d * HC + t * 4) = o;
}

// ---------- bias + layernorm + elu (+residual), fp16 agg in, fp32 (+fp16) out ----------
__global__ __launch_bounds__(256) void ln_elu_kernel(
    const _Float16* __restrict__ agg, const float* __restrict__ bias,
    const float* __restrict__ gam, const float* __restrict__ bet,
    const float* resid, float* out, _Float16* out16, int HC)
{
    int row = blockIdx.x;
    int tid = threadIdx.x;
    int per = HC >> 8;          // 4 for 1024, 1 for 256
    float vr[4];
    const _Float16* ap = agg + (size_t)row * HC;
    float sum = 0.f;
    for (int i = 0; i < per; i++) {
        int c = i * 256 + tid;
        float x = (float)ap[c] + bias[c];
        vr[i] = x; sum += x;
    }
    __shared__ float sm[4];
    #pragma unroll
    for (int o = 32; o; o >>= 1) sum += __shfl_down(sum, o);
    if ((tid & 63) == 0) sm[tid >> 6] = sum;
    __syncthreads();
    float mean = (sm[0] + sm[1] + sm[2] + sm[3]) / (float)HC;
    float sq = 0.f;
    for (int i = 0; i < per; i++) { float dd = vr[i] - mean; sq = fmaf(dd, dd, sq); }
    __syncthreads();
    #pragma unroll
    for (int o = 32; o; o >>= 1) sq += __shfl_down(sq, o);
    if ((tid & 63) == 0) sm[tid >> 6] = sq;
    __syncthreads();
    float var = (sm[0] + sm[1] + sm[2] + sm[3]) / (float)HC;
    float rstd = rsqrtf(var + 1e-5f);
    for (int i = 0; i < per; i++) {
        int c = i * 256 + tid;
        float y = (vr[i] - mean) * rstd * gam[c] + bet[c];
        y = y > 0.f ? y : (expf(y) - 1.f);      // elu
        if (resid) y += resid[(size_t)row * HC + c];
        out[(size_t)row * HC + c] = y;
        if (out16) out16[(size_t)row * HC + c] = (_Float16)y;
    }
}

// ---------- graph pooling: 16 nodes per block, register pre-reduce ----------
__global__ __launch_bounds__(256) void pool_kernel(
    const float* __restrict__ x3, const int* __restrict__ batch,
    float* __restrict__ ps, unsigned* __restrict__ pm, int* __restrict__ cnt, int Nn)
{
    int c = threadIdx.x;
    int n0 = blockIdx.x * 16;
    int end = n0 + 16; if (end > Nn) end = Nn;
    if (n0 >= Nn) return;
    int curg = batch[n0];
    float s = 0.f, m = -1e30f; int k = 0;
    for (int n = n0; n < end; n++) {
        int g = batch[n];
        if (g != curg) {
            atomicAdd(&ps[curg * 256 + c], s);
            atomicMax(&pm[curg * 256 + c], encf(m));
            if (c == 0) atomicAdd(&cnt[curg], k);
            s = 0.f; m = -1e30f; k = 0; curg = g;
        }
        float v = x3[(size_t)n * 256 + c];
        s += v; m = fmaxf(m, v); k++;
    }
    atomicAdd(&ps[curg * 256 + c], s);
    atomicMax(&pm[curg * 256 + c], encf(m));
    if (c == 0) atomicAdd(&cnt[curg], k);
}

// ---------- classifier: [mean|max|sum] @ W1 -> relu -> @ W2 ----------
__global__ __launch_bounds__(128) void classifier_kernel(
    const float* __restrict__ ps, const unsigned* __restrict__ pm, const int* __restrict__ cnt,
    const float* __restrict__ w1, const float* __restrict__ b1,
    const float* __restrict__ w2, const float* __restrict__ b2, float* __restrict__ out)
{
    int g = blockIdx.x;
    int tid = threadIdx.x; // 128
    __shared__ float pooled[768];
    __shared__ float red[2];
    float c = (float)cnt[g];
    if (c < 1.f) c = 1.f;
    for (int i = tid; i < 256; i += 128) {
        float s = ps[g * 256 + i];
        pooled[i] = s / c;
        pooled[256 + i] = decf(pm[g * 256 + i]);
        pooled[512 + i] = s;
    }
    __syncthreads();
    float acc = b1[tid];
    for (int k = 0; k < 768; k++) acc = fmaf(pooled[k], w1[k * 128 + tid], acc);
    acc = fmaxf(acc, 0.f);
    float v = acc * w2[tid];
    #pragma unroll
    for (int o = 32; o; o >>= 1) v += __shfl_down(v, o);
    if ((tid & 63) == 0) red[tid >> 6] = v;
    __syncthreads();
    if (tid == 0) out[g] = red[0] + red[1] + b2[0];
}

// ---------- launcher ----------
extern "C" void kernel_launch(void* const* d_in, const int* in_sizes, int n_in,
                              void* d_out, int out_size, void* d_ws, size_t ws_size,
                              hipStream_t stream)
{
    const float* x      = (const float*)d_in[0];
    const int*   ei     = (const int*)d_in[1];
    const int*   batch  = (const int*)d_in[2];
    const float* proj_w = (const float*)d_in[3];
    const float* proj_b = (const float*)d_in[4];
    const float* gat1_w = (const float*)d_in[5];
    const float* att1_s = (const float*)d_in[6];
    const float* att1_d = (const float*)d_in[7];
    const float* gat1_b = (const float*)d_in[8];
    const float* ln1_g  = (const float*)d_in[9];
    const float* ln1_b  = (const float*)d_in[10];
    const float* gat2_w = (const float*)d_in[11];
    const float* att2_s = (const float*)d_in[12];
    const float* att2_d = (const float*)d_in[13];
    const float* gat2_b = (const float*)d_in[14];
    const float* ln2_g  = (const float*)d_in[15];
    const float* ln2_b  = (const float*)d_in[16];
    const float* gat3_w = (const float*)d_in[17];
    const float* att3_s = (const float*)d_in[18];
    const float* att3_d = (const float*)d_in[19];
    const float* gat3_b = (const float*)d_in[20];
    const float* ln3_g  = (const float*)d_in[21];
    const float* ln3_b  = (const float*)d_in[22];
    const float* cls1_w = (const float*)d_in[23];
    const float* cls1_b = (const float*)d_in[24];
    const float* cls2_w = (const float*)d_in[25];
    const float* cls2_b = (const float*)d_in[26];

    int Nn = in_sizes[0] / 768;
    int E  = in_sizes[1] / 2;
    int Gg = out_size;           // 32
    int Etot = E + Nn;
    int nb  = (Nn + 255) / 256;

    // ---- workspace: P,Q,R fp16 (N*1024) + X fp32 (N*1024) + wT + scratch ~213 MB ----
    char* w = (char*)d_ws;
    size_t NB16 = (size_t)Nn * 1024 * sizeof(_Float16);
    size_t NB32 = (size_t)Nn * 1024 * sizeof(float);
    _Float16* P = (_Float16*)(w);                 // x16 -> h1 -> h2 -> h3
    _Float16* Q = (_Float16*)(w + NB16);          // hproj16 -> x1_16 -> x2_16
    _Float16* R = (_Float16*)(w + 2 * NB16);      // agg fp16 each layer
    float*  X = (float*)(w + 3 * NB16);           // x1/x2 fp32 resid chain -> x3
    char* p = w + 3 * NB16 + NB32;
    _Float16* projT = (_Float16*)p; p += (size_t)768 * 768 * 2;
    _Float16* g1T   = (_Float16*)p; p += (size_t)1024 * 768 * 2;
    _Float16* g2T   = (_Float16*)p; p += (size_t)1024 * 1024 * 2;
    _Float16* g3T   = (_Float16*)p; p += (size_t)256 * 1024 * 2;
    float*    es    = (float*)p;  p += (size_t)Nn * 4 * 4;
    float*    ed_   = (float*)p;  p += (size_t)Nn * 4 * 4;
    int*      deg   = (int*)p;    p += (size_t)Nn * 4;
    int*      incl  = (int*)p;    p += (size_t)Nn * 4;
    int*      rowst = (int*)p;    p += (size_t)Nn * 4;
    int*      curs  = (int*)p;    p += (size_t)Nn * 4;
    int*      bsums = (int*)p;    p += (size_t)nb * 4 + 64;
    int*      csrc  = (int*)p;    p += (size_t)Etot * 4;
    float*    ps    = (float*)p;  p += (size_t)Gg * 256 * 4;
    unsigned* pm    = (unsigned*)p; p += (size_t)Gg * 256 * 4;
    int*      cnt   = (int*)p;    p += 256;

    dim3 blk(256);

    // ---- weight transpose+convert (once per call) ----
    wt_kernel<<<dim3(768 / 32, 768 / 32), blk, 0, stream>>>(proj_w, projT, 768, 768);
    wt_kernel<<<dim3(1024 / 32, 768 / 32), blk, 0, stream>>>(gat1_w, g1T, 768, 1024);
    wt_kernel<<<dim3(1024 / 32, 1024 / 32), blk, 0, stream>>>(gat2_w, g2T, 1024, 1024);
    wt_kernel<<<dim3(256 / 32, 1024 / 32), blk, 0, stream>>>(gat3_w, g3T, 1024, 256);

    // ---- x -> fp16 ----
    {
        size_t n4 = (size_t)Nn * 768 / 4;
        cvt_f16_kernel<<<dim3((unsigned)((n4 + 255) / 256)), blk, 0, stream>>>(x, P, n4);
    }

    // ---- CSR by dst ----
    csr_init<<<dim3(nb), blk, 0, stream>>>(deg, Nn);
    csr_count<<<dim3((E + 255) / 256), blk, 0, stream>>>(ei, deg, E);
    scan1<<<dim3(nb), blk, 0, stream>>>(deg, incl, bsums, Nn);
    scan2<<<dim3(1), dim3(64), 0, stream>>>(bsums, nb);
    scan3<<<dim3(nb), blk, 0, stream>>>(incl, deg, bsums, rowst, curs, Nn);
    csr_fill<<<dim3((Etot + 255) / 256), blk, 0, stream>>>(ei, curs, csrc, E, Nn);

    int mg = (Nn + 127) / 128;

    // proj: hproj16 = elu(x16 @ projW + b) -> Q
    gemm_f16<<<dim3(768 / 128, mg), blk, 0, stream>>>(P, projT, proj_b, Q, Nn, 768, 768, 1);

    auto run_gat = [&](const _Float16* xin16, const _Float16* WT, const float* as_, const float* ad_,
                       const float* gb, const float* lg, const float* lb, const float* resid,
                       _Float16* hbuf, _Float16* aggbuf, float* xout, _Float16* xout16,
                       int K, int H, int C) {
        int HC = H * C;
        gemm_f16<<<dim3(HC / 128, mg), blk, 0, stream>>>(xin16, WT, nullptr, hbuf, Nn, K, HC, 0);
        int nw = Nn * H;
        attn_scores_kernel<<<dim3((nw + 3) / 4), blk, 0, stream>>>(hbuf, as_, ad_, es, ed_, Nn, H);
        if (H == 4)
            gat_aggregate<4><<<dim3(Nn), dim3(256), 0, stream>>>(rowst, deg, csrc, es, ed_, hbuf, aggbuf);
        else
            gat_aggregate<1><<<dim3(Nn), dim3(64), 0, stream>>>(rowst, deg, csrc, es, ed_, hbuf, aggbuf);
        ln_elu_kernel<<<dim3(Nn), blk, 0, stream>>>(aggbuf, gb, lg, lb, resid, xout, xout16, HC);
    };

    // layer 1: 768 -> 4x256. A=Q(hproj) -> h1 in P; x1 -> X (fp32) + Q (fp16)
    run_gat(Q, g1T, att1_s, att1_d, gat1_b, ln1_g, ln1_b, nullptr, P, R, X, Q, 768, 4, 256);
    // layer 2: 1024 -> 4x256, resid x1 (X). A=Q(x1_16) -> h2 in P; x2 -> X in place + Q
    run_gat(Q, g2T, att2_s, att2_d, gat2_b, ln2_g, ln2_b, X, P, R, X, Q, 1024, 4, 256);
    // layer 3: 1024 -> 256 (1 head). A=Q(x2_16) -> h3 in P; x3 -> X fp32 only
    run_gat(Q, g3T, att3_s, att3_d, gat3_b, ln3_g, ln3_b, nullptr, P, R, X, nullptr, 1024, 1, 256);

    // pooling + classifier
    hipMemsetAsync(ps, 0, (size_t)Gg * 256 * 4, stream);
    hipMemsetAsync(pm, 0, (size_t)Gg * 256 * 4, stream);
    hipMemsetAsync(cnt, 0, (size_t)Gg * 4, stream);
    pool_kernel<<<dim3((Nn + 15) / 16), blk, 0, stream>>>(X, batch, ps, pm, cnt, Nn);
    classifier_kernel<<<dim3(Gg), dim3(128), 0, stream>>>(ps, pm, cnt, cls1_w, cls1_b, cls2_w, cls2_b, (float*)d_out);
}

// Round 6
// 926.783 us; speedup vs baseline: 13.5127x; 1.0172x over previous
//
#include <hip/hip_runtime.h>
#include <math.h>

typedef float floatx4 __attribute__((ext_vector_type(4)));
typedef _Float16 f16x8 __attribute__((ext_vector_type(8)));
typedef _Float16 f16x4 __attribute__((ext_vector_type(4)));

// ---------- helpers ----------
__device__ __forceinline__ unsigned encf(float f) {
    unsigned u = __float_as_uint(f);
    return (u & 0x80000000u) ? ~u : (u | 0x80000000u);
}
__device__ __forceinline__ float decf(unsigned u) {
    u = (u & 0x80000000u) ? (u & 0x7FFFFFFFu) : ~u;
    return __uint_as_float(u);
}
// async global->LDS, 16 B per lane; LDS dst = wave-uniform base + lane*16
__device__ __forceinline__ void glds16(const void* g, void* l) {
    __builtin_amdgcn_global_load_lds(
        (const __attribute__((address_space(1))) unsigned int*)g,
        (__attribute__((address_space(3))) unsigned int*)l, 16, 0, 0);
}

// ---------- fp32 -> fp16 convert (vec4) ----------
__global__ __launch_bounds__(256) void cvt_f16_kernel(
    const float* __restrict__ in, _Float16* __restrict__ out, size_t n4)
{
    size_t i = (size_t)blockIdx.x * 256 + threadIdx.x;
    if (i >= n4) return;
    float4 v = ((const float4*)in)[i];
    f16x4 o;
    o[0] = (_Float16)v.x; o[1] = (_Float16)v.y; o[2] = (_Float16)v.z; o[3] = (_Float16)v.w;
    ((f16x4*)out)[i] = o;
}

// ---------- weight transpose + convert: w[K,N] fp32 -> wt[N,K] fp16 ----------
__global__ __launch_bounds__(256) void wt_kernel(
    const float* __restrict__ w, _Float16* __restrict__ wt, int K, int N)
{
    __shared__ float t[32][33];
    int bx = blockIdx.x * 32, by = blockIdx.y * 32;   // bx: n, by: k
    int tx = threadIdx.x & 31, ty = threadIdx.x >> 5; // 32x8
    for (int r = ty; r < 32; r += 8)
        t[r][tx] = w[(size_t)(by + r) * N + bx + tx];
    __syncthreads();
    for (int r = ty; r < 32; r += 8)
        wt[(size_t)(bx + r) * K + by + tx] = (_Float16)t[tx][r];
}

// ---------- fp16 MFMA GEMM, m97-style global_load_lds staging ----------
// C[M,N] = A[M,K] @ B, BT=[N,K]. 128x128 tile, BK=32, 256 threads.
__global__ __launch_bounds__(256) void gemm_f16(
    const _Float16* __restrict__ A, const _Float16* __restrict__ BT,
    const float* __restrict__ bias, _Float16* __restrict__ C,
    int M, int K, int N, int act)
{
    __shared__ _Float16 Al[128 * 32];
    __shared__ _Float16 Bl[128 * 32];
    int tid = threadIdx.x;
    int lane = tid & 63, wave = tid >> 6;
    int row0 = blockIdx.y * 128, col0 = blockIdx.x * 128;
    int wm = (wave >> 1) * 64, wn = (wave & 1) * 64;
    int l15 = lane & 15, quad = lane >> 4;

    // staging: wave w covers rowgroups {2w,2w+1} (16 rows each) of A and B.
    // lane i -> row rg*16 + i/4, f16 cols [(i&3)*8, +8): LDS offset = 16*i B.
    int rg0 = wave * 2, rg1 = rg0 + 1;
    int srow0 = rg0 * 16 + (lane >> 2);
    int srow1 = rg1 * 16 + (lane >> 2);
    int scol = (lane & 3) * 8;
    int arow0 = row0 + srow0; if (arow0 > M - 1) arow0 = M - 1;
    int arow1 = row0 + srow1; if (arow1 > M - 1) arow1 = M - 1;
    const _Float16* gA0 = A + (size_t)arow0 * K + scol;
    const _Float16* gA1 = A + (size_t)arow1 * K + scol;
    const _Float16* gB0 = BT + (size_t)(col0 + srow0) * K + scol;
    const _Float16* gB1 = BT + (size_t)(col0 + srow1) * K + scol;
    _Float16* lA0 = &Al[rg0 * 512];
    _Float16* lA1 = &Al[rg1 * 512];
    _Float16* lB0 = &Bl[rg0 * 512];
    _Float16* lB1 = &Bl[rg1 * 512];

    floatx4 acc[4][4] = {};

    for (int k0 = 0; k0 < K; k0 += 32) {
        glds16(gA0 + k0, lA0);
        glds16(gA1 + k0, lA1);
        glds16(gB0 + k0, lB0);
        glds16(gB1 + k0, lB1);
        __syncthreads();                 // drains vmcnt: staging visible
        f16x8 af[4], bfr[4];
        #pragma unroll
        for (int i = 0; i < 4; i++) {
            af[i]  = *(const f16x8*)&Al[(wm + i * 16 + l15) * 32 + quad * 8];
            bfr[i] = *(const f16x8*)&Bl[(wn + i * 16 + l15) * 32 + quad * 8];
        }
        #pragma unroll
        for (int i = 0; i < 4; i++)
            #pragma unroll
            for (int j = 0; j < 4; j++)
                acc[i][j] = __builtin_amdgcn_mfma_f32_16x16x32_f16(af[i], bfr[j], acc[i][j], 0, 0, 0);
        __syncthreads();                 // all ds_reads done before re-stage
    }

    // epilogue: D row = quad*4+reg, col = l15
    #pragma unroll
    for (int i = 0; i < 4; i++) {
        #pragma unroll
        for (int v = 0; v < 4; v++) {
            int gr = row0 + wm + i * 16 + quad * 4 + v;
            if (gr >= M) continue;
            #pragma unroll
            for (int j = 0; j < 4; j++) {
                int gc = col0 + wn + j * 16 + l15;
                float val = acc[i][j][v];
                if (bias) val += bias[gc];
                if (act) val = val > 0.f ? val : (expf(val) - 1.f);
                C[(size_t)gr * N + gc] = (_Float16)val;
            }
        }
    }
}

// ---------- per-(node,head) attention scores from fp16 h ----------
__global__ __launch_bounds__(256) void attn_scores_kernel(
    const _Float16* __restrict__ h, const float* __restrict__ asrc, const float* __restrict__ adst,
    float* __restrict__ es, float* __restrict__ ed, int Nn, int H)
{
    int wid = (blockIdx.x * 256 + threadIdx.x) >> 6;
    int lane = threadIdx.x & 63;
    if (wid >= Nn * H) return;
    int node = wid / H, hh = wid % H;
    const _Float16* hp = h + (size_t)node * H * 256 + hh * 256 + lane * 4;
    f16x4 v = *(const f16x4*)hp;
    float ss = 0.f, sd = 0.f;
    #pragma unroll
    for (int j = 0; j < 4; j++) {
        float f = (float)v[j];
        ss = fmaf(f, asrc[hh * 256 + lane * 4 + j], ss);
        sd = fmaf(f, adst[hh * 256 + lane * 4 + j], sd);
    }
    #pragma unroll
    for (int o = 32; o; o >>= 1) { ss += __shfl_down(ss, o); sd += __shfl_down(sd, o); }
    if (lane == 0) { es[wid] = ss; ed[wid] = sd; }
}

// ---------- CSR build ----------
__global__ __launch_bounds__(256) void csr_init(int* __restrict__ deg, int Nn) {
    int i = blockIdx.x * 256 + threadIdx.x;
    if (i < Nn) deg[i] = 1;               // self-loop
}
__global__ __launch_bounds__(256) void csr_count(const int* __restrict__ ei, int* __restrict__ deg, int E) {
    int i = blockIdx.x * 256 + threadIdx.x;
    if (i < E) atomicAdd(&deg[ei[E + i]], 1);
}
__global__ __launch_bounds__(256) void scan1(const int* __restrict__ deg, int* __restrict__ incl,
                                             int* __restrict__ bsums, int Nn) {
    __shared__ int sd[256];
    int idx = blockIdx.x * 256 + threadIdx.x;
    sd[threadIdx.x] = (idx < Nn) ? deg[idx] : 0;
    __syncthreads();
    for (int o = 1; o < 256; o <<= 1) {
        int x = (threadIdx.x >= (unsigned)o) ? sd[threadIdx.x - o] : 0;
        __syncthreads();
        sd[threadIdx.x] += x;
        __syncthreads();
    }
    if (idx < Nn) incl[idx] = sd[threadIdx.x];
    if (threadIdx.x == 255) bsums[blockIdx.x] = sd[255];
}
__global__ void scan2(int* __restrict__ bsums, int nb) {
    if (blockIdx.x == 0 && threadIdx.x == 0) {
        int run = 0;
        for (int i = 0; i < nb; i++) { int v = bsums[i]; bsums[i] = run; run += v; }
    }
}
__global__ __launch_bounds__(256) void scan3(const int* __restrict__ incl, const int* __restrict__ deg,
                                             const int* __restrict__ bsums, int* __restrict__ rowstart,
                                             int* __restrict__ cursor, int Nn) {
    int idx = blockIdx.x * 256 + threadIdx.x;
    if (idx >= Nn) return;
    int rs = incl[idx] - deg[idx] + bsums[blockIdx.x];
    rowstart[idx] = rs;
    cursor[idx] = rs;
}
__global__ __launch_bounds__(256) void csr_fill(const int* __restrict__ ei, int* __restrict__ cursor,
                                                int* __restrict__ csrc, int* __restrict__ cdst,
                                                int E, int Nn) {
    int i = blockIdx.x * 256 + threadIdx.x;
    if (i >= E + Nn) return;
    int s, d;
    if (i < E) { s = ei[i]; d = ei[E + i]; } else { s = d = i - E; }
    int pos = atomicAdd(&cursor[d], 1);
    csrc[pos] = s;
    cdst[pos] = d;
}

// ---------- segment softmax stats: per (dst,head) max + 1/sum ----------
// one wave per dst node
template<int H>
__global__ __launch_bounds__(256) void seg_mz(
    const int* __restrict__ rowstart, const int* __restrict__ deg,
    const int* __restrict__ csrc, const float* __restrict__ es,
    const float* __restrict__ ed, float2* __restrict__ mz, int Nn)
{
    int d = (blockIdx.x * 256 + threadIdx.x) >> 6;
    int lane = threadIdx.x & 63;
    if (d >= Nn) return;
    constexpr int S = 64 / H;
    int head = lane & (H - 1);
    int slot = lane / H;
    int st = rowstart[d], dg = deg[d];
    float edv = ed[d * H + head];
    float m = -1e30f;
    for (int j = slot; j < dg; j += S) {
        float l = es[csrc[st + j] * H + head] + edv;
        l = l > 0.f ? l : 0.2f * l;
        m = fmaxf(m, l);
    }
    #pragma unroll
    for (int o = H; o < 64; o <<= 1) m = fmaxf(m, __shfl_xor(m, o));
    float z = 0.f;
    for (int j = slot; j < dg; j += S) {
        float l = es[csrc[st + j] * H + head] + edv;
        l = l > 0.f ? l : 0.2f * l;
        z += expf(l - m);
    }
    #pragma unroll
    for (int o = H; o < 64; o <<= 1) z += __shfl_xor(z, o);
    if (lane < H) mz[d * H + lane] = make_float2(m, 1.f / (z + 1e-16f));
}

// ---------- per-CSR-entry alpha (all H heads), written once ----------
template<int H>
__global__ __launch_bounds__(256) void edge_alpha(
    const int* __restrict__ csrc, const int* __restrict__ cdst,
    const float* __restrict__ es, const float* __restrict__ ed,
    const float2* __restrict__ mz, float* __restrict__ wse, int Etot)
{
    int i = blockIdx.x * 256 + threadIdx.x;
    if (i >= Etot) return;
    int s = csrc[i], d = cdst[i];
    float a[H];
    #pragma unroll
    for (int hh = 0; hh < H; hh++) {
        float l = es[s * H + hh] + ed[d * H + hh];
        l = l > 0.f ? l : 0.2f * l;
        float2 mzv = mz[d * H + hh];
        a[hh] = expf(l - mzv.x) * mzv.y;
    }
    #pragma unroll
    for (int hh = 0; hh < H; hh++) wse[(size_t)i * H + hh] = a[hh];
}

// ---------- pure gather: out[d] = sum alpha_j * h[src_j], alphas precomputed ----------
template<int H>
__global__ __launch_bounds__(64 * H) void gat_gather(
    const int* __restrict__ rowstart, const int* __restrict__ deg,
    const int* __restrict__ csrc, const float* __restrict__ wse,
    const _Float16* __restrict__ h, _Float16* __restrict__ out)
{
    constexpr int T = 64 * H;
    const int HC = T * 4;
    int d = blockIdx.x;
    int t = threadIdx.x;
    int head2 = t >> 6;
    int st = rowstart[d], dg = deg[d];
    const _Float16* hb = h + (size_t)t * 4;
    float acc0 = 0.f, acc1 = 0.f, acc2 = 0.f, acc3 = 0.f;
    // 2-stage pipeline; dg >= 1 guaranteed (self-loop)
    int s = csrc[st];
    float a = wse[(size_t)st * H + head2];
    for (int j = 1; j < dg; j++) {
        int s_n = csrc[st + j];
        float a_n = wse[(size_t)(st + j) * H + head2];
        f16x4 v = *(const f16x4*)(hb + (size_t)s * HC);
        acc0 = fmaf(a, (float)v[0], acc0);
        acc1 = fmaf(a, (float)v[1], acc1);
        acc2 = fmaf(a, (float)v[2], acc2);
        acc3 = fmaf(a, (float)v[3], acc3);
        s = s_n; a = a_n;
    }
    f16x4 v = *(const f16x4*)(hb + (size_t)s * HC);
    acc0 = fmaf(a, (float)v[0], acc0);
    acc1 = fmaf(a, (float)v[1], acc1);
    acc2 = fmaf(a, (float)v[2], acc2);
    acc3 = fmaf(a, (float)v[3], acc3);
    f16x4 o;
    o[0] = (_Float16)acc0; o[1] = (_Float16)acc1; o[2] = (_Float16)acc2; o[3] = (_Float16)acc3;
    *(f16x4*)(out + (size_t)d * HC + t * 4) = o;
}

// ---------- bias + layernorm + elu (+residual), fp16 agg in, fp32 (+fp16) out ----------
__global__ __launch_bounds__(256) void ln_elu_kernel(
    const _Float16* __restrict__ agg, const float* __restrict__ bias,
    const float* __restrict__ gam, const float* __restrict__ bet,
    const float* resid, float* out, _Float16* out16, int HC)
{
    int row = blockIdx.x;
    int tid = threadIdx.x;
    int per = HC >> 8;          // 4 for 1024, 1 for 256
    float vr[4];
    const _Float16* ap = agg + (size_t)row * HC;
    float sum = 0.f;
    for (int i = 0; i < per; i++) {
        int c = i * 256 + tid;
        float x = (float)ap[c] + bias[c];
        vr[i] = x; sum += x;
    }
    __shared__ float sm[4];
    #pragma unroll
    for (int o = 32; o; o >>= 1) sum += __shfl_down(sum, o);
    if ((tid & 63) == 0) sm[tid >> 6] = sum;
    __syncthreads();
    float mean = (sm[0] + sm[1] + sm[2] + sm[3]) / (float)HC;
    float sq = 0.f;
    for (int i = 0; i < per; i++) { float dd = vr[i] - mean; sq = fmaf(dd, dd, sq); }
    __syncthreads();
    #pragma unroll
    for (int o = 32; o; o >>= 1) sq += __shfl_down(sq, o);
    if ((tid & 63) == 0) sm[tid >> 6] = sq;
    __syncthreads();
    float var = (sm[0] + sm[1] + sm[2] + sm[3]) / (float)HC;
    float rstd = rsqrtf(var + 1e-5f);
    for (int i = 0; i < per; i++) {
        int c = i * 256 + tid;
        float y = (vr[i] - mean) * rstd * gam[c] + bet[c];
        y = y > 0.f ? y : (expf(y) - 1.f);      // elu
        if (resid) y += resid[(size_t)row * HC + c];
        out[(size_t)row * HC + c] = y;
        if (out16) out16[(size_t)row * HC + c] = (_Float16)y;
    }
}

// ---------- graph pooling: 16 nodes per block, register pre-reduce ----------
__global__ __launch_bounds__(256) void pool_kernel(
    const float* __restrict__ x3, const int* __restrict__ batch,
    float* __restrict__ ps, unsigned* __restrict__ pm, int* __restrict__ cnt, int Nn)
{
    int c = threadIdx.x;
    int n0 = blockIdx.x * 16;
    int end = n0 + 16; if (end > Nn) end = Nn;
    if (n0 >= Nn) return;
    int curg = batch[n0];
    float s = 0.f, m = -1e30f; int k = 0;
    for (int n = n0; n < end; n++) {
        int g = batch[n];
        if (g != curg) {
            atomicAdd(&ps[curg * 256 + c], s);
            atomicMax(&pm[curg * 256 + c], encf(m));
            if (c == 0) atomicAdd(&cnt[curg], k);
            s = 0.f; m = -1e30f; k = 0; curg = g;
        }
        float v = x3[(size_t)n * 256 + c];
        s += v; m = fmaxf(m, v); k++;
    }
    atomicAdd(&ps[curg * 256 + c], s);
    atomicMax(&pm[curg * 256 + c], encf(m));
    if (c == 0) atomicAdd(&cnt[curg], k);
}

// ---------- classifier: [mean|max|sum] @ W1 -> relu -> @ W2 ----------
__global__ __launch_bounds__(128) void classifier_kernel(
    const float* __restrict__ ps, const unsigned* __restrict__ pm, const int* __restrict__ cnt,
    const float* __restrict__ w1, const float* __restrict__ b1,
    const float* __restrict__ w2, const float* __restrict__ b2, float* __restrict__ out)
{
    int g = blockIdx.x;
    int tid = threadIdx.x; // 128
    __shared__ float pooled[768];
    __shared__ float red[2];
    float c = (float)cnt[g];
    if (c < 1.f) c = 1.f;
    for (int i = tid; i < 256; i += 128) {
        float s = ps[g * 256 + i];
        pooled[i] = s / c;
        pooled[256 + i] = decf(pm[g * 256 + i]);
        pooled[512 + i] = s;
    }
    __syncthreads();
    float acc = b1[tid];
    for (int k = 0; k < 768; k++) acc = fmaf(pooled[k], w1[k * 128 + tid], acc);
    acc = fmaxf(acc, 0.f);
    float v = acc * w2[tid];
    #pragma unroll
    for (int o = 32; o; o >>= 1) v += __shfl_down(v, o);
    if ((tid & 63) == 0) red[tid >> 6] = v;
    __syncthreads();
    if (tid == 0) out[g] = red[0] + red[1] + b2[0];
}

// ---------- launcher ----------
extern "C" void kernel_launch(void* const* d_in, const int* in_sizes, int n_in,
                              void* d_out, int out_size, void* d_ws, size_t ws_size,
                              hipStream_t stream)
{
    const float* x      = (const float*)d_in[0];
    const int*   ei     = (const int*)d_in[1];
    const int*   batch  = (const int*)d_in[2];
    const float* proj_w = (const float*)d_in[3];
    const float* proj_b = (const float*)d_in[4];
    const float* gat1_w = (const float*)d_in[5];
    const float* att1_s = (const float*)d_in[6];
    const float* att1_d = (const float*)d_in[7];
    const float* gat1_b = (const float*)d_in[8];
    const float* ln1_g  = (const float*)d_in[9];
    const float* ln1_b  = (const float*)d_in[10];
    const float* gat2_w = (const float*)d_in[11];
    const float* att2_s = (const float*)d_in[12];
    const float* att2_d = (const float*)d_in[13];
    const float* gat2_b = (const float*)d_in[14];
    const float* ln2_g  = (const float*)d_in[15];
    const float* ln2_b  = (const float*)d_in[16];
    const float* gat3_w = (const float*)d_in[17];
    const float* att3_s = (const float*)d_in[18];
    const float* att3_d = (const float*)d_in[19];
    const float* gat3_b = (const float*)d_in[20];
    const float* ln3_g  = (const float*)d_in[21];
    const float* ln3_b  = (const float*)d_in[22];
    const float* cls1_w = (const float*)d_in[23];
    const float* cls1_b = (const float*)d_in[24];
    const float* cls2_w = (const float*)d_in[25];
    const float* cls2_b = (const float*)d_in[26];

    int Nn = in_sizes[0] / 768;
    int E  = in_sizes[1] / 2;
    int Gg = out_size;           // 32
    int Etot = E + Nn;
    int nb  = (Nn + 255) / 256;

    // ---- workspace layout (aligned to 256 B), ~220 MB ----
    char* w = (char*)d_ws;
    size_t off = 0;
    auto alloc = [&](size_t bytes) -> char* {
        char* r = w + off;
        off += (bytes + 255) & ~(size_t)255;
        return r;
    };
    size_t NB16 = (size_t)Nn * 1024 * sizeof(_Float16);
    size_t NB32 = (size_t)Nn * 1024 * sizeof(float);
    _Float16* P = (_Float16*)alloc(NB16);     // x16 -> h1 -> h2 -> h3
    _Float16* Q = (_Float16*)alloc(NB16);     // hproj16 -> x1_16 -> x2_16
    _Float16* R = (_Float16*)alloc(NB16);     // agg fp16 each layer
    float*  X = (float*)alloc(NB32);          // x1/x2 fp32 resid chain -> x3
    _Float16* projT = (_Float16*)alloc((size_t)768 * 768 * 2);
    _Float16* g1T   = (_Float16*)alloc((size_t)1024 * 768 * 2);
    _Float16* g2T   = (_Float16*)alloc((size_t)1024 * 1024 * 2);
    _Float16* g3T   = (_Float16*)alloc((size_t)256 * 1024 * 2);
    float*    es    = (float*)alloc((size_t)Nn * 4 * 4);
    float*    ed_   = (float*)alloc((size_t)Nn * 4 * 4);
    float2*   mz    = (float2*)alloc((size_t)Nn * 4 * 8);
    int*      deg   = (int*)alloc((size_t)Nn * 4);
    int*      incl  = (int*)alloc((size_t)Nn * 4);
    int*      rowst = (int*)alloc((size_t)Nn * 4);
    int*      curs  = (int*)alloc((size_t)Nn * 4);
    int*      bsums = (int*)alloc((size_t)nb * 4);
    int*      csrc  = (int*)alloc((size_t)Etot * 4);
    int*      cdst  = (int*)alloc((size_t)Etot * 4);
    float*    wse   = (float*)alloc((size_t)Etot * 4 * 4);
    float*    ps    = (float*)alloc((size_t)Gg * 256 * 4);
    unsigned* pm    = (unsigned*)alloc((size_t)Gg * 256 * 4);
    int*      cnt   = (int*)alloc(256);

    dim3 blk(256);

    // ---- weight transpose+convert ----
    wt_kernel<<<dim3(768 / 32, 768 / 32), blk, 0, stream>>>(proj_w, projT, 768, 768);
    wt_kernel<<<dim3(1024 / 32, 768 / 32), blk, 0, stream>>>(gat1_w, g1T, 768, 1024);
    wt_kernel<<<dim3(1024 / 32, 1024 / 32), blk, 0, stream>>>(gat2_w, g2T, 1024, 1024);
    wt_kernel<<<dim3(256 / 32, 1024 / 32), blk, 0, stream>>>(gat3_w, g3T, 1024, 256);

    // ---- x -> fp16 ----
    {
        size_t n4 = (size_t)Nn * 768 / 4;
        cvt_f16_kernel<<<dim3((unsigned)((n4 + 255) / 256)), blk, 0, stream>>>(x, P, n4);
    }

    // ---- CSR by dst ----
    csr_init<<<dim3(nb), blk, 0, stream>>>(deg, Nn);
    csr_count<<<dim3((E + 255) / 256), blk, 0, stream>>>(ei, deg, E);
    scan1<<<dim3(nb), blk, 0, stream>>>(deg, incl, bsums, Nn);
    scan2<<<dim3(1), dim3(64), 0, stream>>>(bsums, nb);
    scan3<<<dim3(nb), blk, 0, stream>>>(incl, deg, bsums, rowst, curs, Nn);
    csr_fill<<<dim3((Etot + 255) / 256), blk, 0, stream>>>(ei, curs, csrc, cdst, E, Nn);

    int mg = (Nn + 127) / 128;

    // proj: hproj16 = elu(x16 @ projW + b) -> Q
    gemm_f16<<<dim3(768 / 128, mg), blk, 0, stream>>>(P, projT, proj_b, Q, Nn, 768, 768, 1);

    auto run_gat = [&](const _Float16* xin16, const _Float16* WT, const float* as_, const float* ad_,
                       const float* gb, const float* lg, const float* lb, const float* resid,
                       _Float16* hbuf, _Float16* aggbuf, float* xout, _Float16* xout16,
                       int K, int H, int C) {
        int HC = H * C;
        gemm_f16<<<dim3(HC / 128, mg), blk, 0, stream>>>(xin16, WT, nullptr, hbuf, Nn, K, HC, 0);
        int nw = Nn * H;
        attn_scores_kernel<<<dim3((nw + 3) / 4), blk, 0, stream>>>(hbuf, as_, ad_, es, ed_, Nn, H);
        if (H == 4) {
            seg_mz<4><<<dim3((Nn + 3) / 4), blk, 0, stream>>>(rowst, deg, csrc, es, ed_, mz, Nn);
            edge_alpha<4><<<dim3((Etot + 255) / 256), blk, 0, stream>>>(csrc, cdst, es, ed_, mz, wse, Etot);
            gat_gather<4><<<dim3(Nn), dim3(256), 0, stream>>>(rowst, deg, csrc, wse, hbuf, aggbuf);
        } else {
            seg_mz<1><<<dim3((Nn + 3) / 4), blk, 0, stream>>>(rowst, deg, csrc, es, ed_, mz, Nn);
            edge_alpha<1><<<dim3((Etot + 255) / 256), blk, 0, stream>>>(csrc, cdst, es, ed_, mz, wse, Etot);
            gat_gather<1><<<dim3(Nn), dim3(64), 0, stream>>>(rowst, deg, csrc, wse, hbuf, aggbuf);
        }
        ln_elu_kernel<<<dim3(Nn), blk, 0, stream>>>(aggbuf, gb, lg, lb, resid, xout, xout16, HC);
    };

    // layer 1: 768 -> 4x256. A=Q(hproj) -> h1 in P; x1 -> X (fp32) + Q (fp16)
    run_gat(Q, g1T, att1_s, att1_d, gat1_b, ln1_g, ln1_b, nullptr, P, R, X, Q, 768, 4, 256);
    // layer 2: 1024 -> 4x256, resid x1 (X). A=Q(x1_16) -> h2 in P; x2 -> X in place + Q
    run_gat(Q, g2T, att2_s, att2_d, gat2_b, ln2_g, ln2_b, X, P, R, X, Q, 1024, 4, 256);
    // layer 3: 1024 -> 256 (1 head). A=Q(x2_16) -> h3 in P; x3 -> X fp32 only
    run_gat(Q, g3T, att3_s, att3_d, gat3_b, ln3_g, ln3_b, nullptr, P, R, X, nullptr, 1024, 1, 256);

    // pooling + classifier
    hipMemsetAsync(ps, 0, (size_t)Gg * 256 * 4, stream);
    hipMemsetAsync(pm, 0, (size_t)Gg * 256 * 4, stream);
    hipMemsetAsync(cnt, 0, (size_t)Gg * 4, stream);
    pool_kernel<<<dim3((Nn + 15) / 16), blk, 0, stream>>>(X, batch, ps, pm, cnt, Nn);
    classifier_kernel<<<dim3(Gg), dim3(128), 0, stream>>>(ps, pm, cnt, cls1_w, cls1_b, cls2_w, cls2_b, (float*)d_out);
}

// Round 7
// 814.181 us; speedup vs baseline: 15.3815x; 1.1383x over previous
//
#include <hip/hip_runtime.h>
#include <math.h>

typedef float floatx4 __attribute__((ext_vector_type(4)));
typedef _Float16 f16x8 __attribute__((ext_vector_type(8)));
typedef _Float16 f16x4 __attribute__((ext_vector_type(4)));

// ---------- helpers ----------
__device__ __forceinline__ unsigned encf(float f) {
    unsigned u = __float_as_uint(f);
    return (u & 0x80000000u) ? ~u : (u | 0x80000000u);
}
__device__ __forceinline__ float decf(unsigned u) {
    u = (u & 0x80000000u) ? (u & 0x7FFFFFFFu) : ~u;
    return __uint_as_float(u);
}
// async global->LDS, 16 B per lane; LDS dst = wave-uniform base + lane*16
__device__ __forceinline__ void glds16(const void* g, void* l) {
    __builtin_amdgcn_global_load_lds(
        (const __attribute__((address_space(1))) unsigned int*)g,
        (__attribute__((address_space(3))) unsigned int*)l, 16, 0, 0);
}

// ---------- fp32 -> fp16 convert (vec4) ----------
__global__ __launch_bounds__(256) void cvt_f16_kernel(
    const float* __restrict__ in, _Float16* __restrict__ out, size_t n4)
{
    size_t i = (size_t)blockIdx.x * 256 + threadIdx.x;
    if (i >= n4) return;
    float4 v = ((const float4*)in)[i];
    f16x4 o;
    o[0] = (_Float16)v.x; o[1] = (_Float16)v.y; o[2] = (_Float16)v.z; o[3] = (_Float16)v.w;
    ((f16x4*)out)[i] = o;
}

// ---------- weight transpose + convert: w[K,N] fp32 -> wt[N,K] fp16 ----------
__global__ __launch_bounds__(256) void wt_kernel(
    const float* __restrict__ w, _Float16* __restrict__ wt, int K, int N)
{
    __shared__ float t[32][33];
    int bx = blockIdx.x * 32, by = blockIdx.y * 32;   // bx: n, by: k
    int tx = threadIdx.x & 31, ty = threadIdx.x >> 5; // 32x8
    for (int r = ty; r < 32; r += 8)
        t[r][tx] = w[(size_t)(by + r) * N + bx + tx];
    __syncthreads();
    for (int r = ty; r < 32; r += 8)
        wt[(size_t)(bx + r) * K + by + tx] = (_Float16)t[tx][r];
}

// ---------- fp16 MFMA GEMM, double-buffered global_load_lds staging ----------
// C[M,N] = A[M,K] @ B, BT=[N,K]. 128x128 tile, BK=32, 256 threads.
// One barrier per K-step; prefetch of tile k+1 issued AFTER the barrier so it
// flies during tile-k MFMAs and is drained by the NEXT barrier's vmcnt(0).
__global__ __launch_bounds__(256) void gemm_f16(
    const _Float16* __restrict__ A, const _Float16* __restrict__ BT,
    const float* __restrict__ bias, _Float16* __restrict__ C,
    int M, int K, int N, int act)
{
    __shared__ _Float16 Al[2][128 * 32];
    __shared__ _Float16 Bl[2][128 * 32];
    int tid = threadIdx.x;
    int lane = tid & 63, wave = tid >> 6;
    int row0 = blockIdx.y * 128, col0 = blockIdx.x * 128;
    int wm = (wave >> 1) * 64, wn = (wave & 1) * 64;
    int l15 = lane & 15, quad = lane >> 4;

    // staging: wave w covers rowgroups {2w,2w+1} (16 rows each) of A and B.
    // lane i -> row rg*16 + i/4, f16 cols [(i&3)*8, +8): LDS offset = 16*i B.
    int rg0 = wave * 2, rg1 = rg0 + 1;
    int srow0 = rg0 * 16 + (lane >> 2);
    int srow1 = rg1 * 16 + (lane >> 2);
    int scol = (lane & 3) * 8;
    int arow0 = row0 + srow0; if (arow0 > M - 1) arow0 = M - 1;
    int arow1 = row0 + srow1; if (arow1 > M - 1) arow1 = M - 1;
    const _Float16* gA0 = A + (size_t)arow0 * K + scol;
    const _Float16* gA1 = A + (size_t)arow1 * K + scol;
    const _Float16* gB0 = BT + (size_t)(col0 + srow0) * K + scol;
    const _Float16* gB1 = BT + (size_t)(col0 + srow1) * K + scol;

    floatx4 acc[4][4] = {};

    // prologue: stage tile 0 into buffer 0
    glds16(gA0, &Al[0][rg0 * 512]);
    glds16(gA1, &Al[0][rg1 * 512]);
    glds16(gB0, &Bl[0][rg0 * 512]);
    glds16(gB1, &Bl[0][rg1 * 512]);

    int nk = K >> 5;
    for (int it = 0; it < nk; it++) {
        int cur = it & 1, nxt = cur ^ 1;
        __syncthreads();                   // drains this tile's staging (vmcnt)
        if (it + 1 < nk) {                 // prefetch next tile (in flight during MFMA)
            int k1 = (it + 1) << 5;
            glds16(gA0 + k1, &Al[nxt][rg0 * 512]);
            glds16(gA1 + k1, &Al[nxt][rg1 * 512]);
            glds16(gB0 + k1, &Bl[nxt][rg0 * 512]);
            glds16(gB1 + k1, &Bl[nxt][rg1 * 512]);
        }
        f16x8 af[4], bfr[4];
        #pragma unroll
        for (int i = 0; i < 4; i++) {
            af[i]  = *(const f16x8*)&Al[cur][(wm + i * 16 + l15) * 32 + quad * 8];
            bfr[i] = *(const f16x8*)&Bl[cur][(wn + i * 16 + l15) * 32 + quad * 8];
        }
        #pragma unroll
        for (int i = 0; i < 4; i++)
            #pragma unroll
            for (int j = 0; j < 4; j++)
                acc[i][j] = __builtin_amdgcn_mfma_f32_16x16x32_f16(af[i], bfr[j], acc[i][j], 0, 0, 0);
    }

    // epilogue: D row = quad*4+reg, col = l15
    #pragma unroll
    for (int i = 0; i < 4; i++) {
        #pragma unroll
        for (int v = 0; v < 4; v++) {
            int gr = row0 + wm + i * 16 + quad * 4 + v;
            if (gr >= M) continue;
            #pragma unroll
            for (int j = 0; j < 4; j++) {
                int gc = col0 + wn + j * 16 + l15;
                float val = acc[i][j][v];
                if (bias) val += bias[gc];
                if (act) val = val > 0.f ? val : (expf(val) - 1.f);
                C[(size_t)gr * N + gc] = (_Float16)val;
            }
        }
    }
}

// ---------- per-(node,head) attention scores from fp16 h ----------
__global__ __launch_bounds__(256) void attn_scores_kernel(
    const _Float16* __restrict__ h, const float* __restrict__ asrc, const float* __restrict__ adst,
    float* __restrict__ es, float* __restrict__ ed, int Nn, int H)
{
    int wid = (blockIdx.x * 256 + threadIdx.x) >> 6;
    int lane = threadIdx.x & 63;
    if (wid >= Nn * H) return;
    int node = wid / H, hh = wid % H;
    const _Float16* hp = h + (size_t)node * H * 256 + hh * 256 + lane * 4;
    f16x4 v = *(const f16x4*)hp;
    float ss = 0.f, sd = 0.f;
    #pragma unroll
    for (int j = 0; j < 4; j++) {
        float f = (float)v[j];
        ss = fmaf(f, asrc[hh * 256 + lane * 4 + j], ss);
        sd = fmaf(f, adst[hh * 256 + lane * 4 + j], sd);
    }
    #pragma unroll
    for (int o = 32; o; o >>= 1) { ss += __shfl_down(ss, o); sd += __shfl_down(sd, o); }
    if (lane == 0) { es[wid] = ss; ed[wid] = sd; }
}

// ---------- CSR build ----------
__global__ __launch_bounds__(256) void csr_init(int* __restrict__ deg, int Nn) {
    int i = blockIdx.x * 256 + threadIdx.x;
    if (i < Nn) deg[i] = 1;               // self-loop
}
__global__ __launch_bounds__(256) void csr_count(const int* __restrict__ ei, int* __restrict__ deg, int E) {
    int i = blockIdx.x * 256 + threadIdx.x;
    if (i < E) atomicAdd(&deg[ei[E + i]], 1);
}
__global__ __launch_bounds__(256) void scan1(const int* __restrict__ deg, int* __restrict__ incl,
                                             int* __restrict__ bsums, int Nn) {
    __shared__ int sd[256];
    int idx = blockIdx.x * 256 + threadIdx.x;
    sd[threadIdx.x] = (idx < Nn) ? deg[idx] : 0;
    __syncthreads();
    for (int o = 1; o < 256; o <<= 1) {
        int x = (threadIdx.x >= (unsigned)o) ? sd[threadIdx.x - o] : 0;
        __syncthreads();
        sd[threadIdx.x] += x;
        __syncthreads();
    }
    if (idx < Nn) incl[idx] = sd[threadIdx.x];
    if (threadIdx.x == 255) bsums[blockIdx.x] = sd[255];
}
__global__ void scan2(int* __restrict__ bsums, int nb) {
    if (blockIdx.x == 0 && threadIdx.x == 0) {
        int run = 0;
        for (int i = 0; i < nb; i++) { int v = bsums[i]; bsums[i] = run; run += v; }
    }
}
__global__ __launch_bounds__(256) void scan3(const int* __restrict__ incl, const int* __restrict__ deg,
                                             const int* __restrict__ bsums, int* __restrict__ rowstart,
                                             int* __restrict__ cursor, int Nn) {
    int idx = blockIdx.x * 256 + threadIdx.x;
    if (idx >= Nn) return;
    int rs = incl[idx] - deg[idx] + bsums[blockIdx.x];
    rowstart[idx] = rs;
    cursor[idx] = rs;
}
__global__ __launch_bounds__(256) void csr_fill(const int* __restrict__ ei, int* __restrict__ cursor,
                                                int* __restrict__ csrc, int* __restrict__ cdst,
                                                int E, int Nn) {
    int i = blockIdx.x * 256 + threadIdx.x;
    if (i >= E + Nn) return;
    int s, d;
    if (i < E) { s = ei[i]; d = ei[E + i]; } else { s = d = i - E; }
    int pos = atomicAdd(&cursor[d], 1);
    csrc[pos] = s;
    cdst[pos] = d;
}

// ---------- segment softmax stats: per (dst,head) max + 1/sum ----------
template<int H>
__global__ __launch_bounds__(256) void seg_mz(
    const int* __restrict__ rowstart, const int* __restrict__ deg,
    const int* __restrict__ csrc, const float* __restrict__ es,
    const float* __restrict__ ed, float2* __restrict__ mz, int Nn)
{
    int d = (blockIdx.x * 256 + threadIdx.x) >> 6;
    int lane = threadIdx.x & 63;
    if (d >= Nn) return;
    constexpr int S = 64 / H;
    int head = lane & (H - 1);
    int slot = lane / H;
    int st = rowstart[d], dg = deg[d];
    float edv = ed[d * H + head];
    float m = -1e30f;
    for (int j = slot; j < dg; j += S) {
        float l = es[csrc[st + j] * H + head] + edv;
        l = l > 0.f ? l : 0.2f * l;
        m = fmaxf(m, l);
    }
    #pragma unroll
    for (int o = H; o < 64; o <<= 1) m = fmaxf(m, __shfl_xor(m, o));
    float z = 0.f;
    for (int j = slot; j < dg; j += S) {
        float l = es[csrc[st + j] * H + head] + edv;
        l = l > 0.f ? l : 0.2f * l;
        z += expf(l - m);
    }
    #pragma unroll
    for (int o = H; o < 64; o <<= 1) z += __shfl_xor(z, o);
    if (lane < H) mz[d * H + lane] = make_float2(m, 1.f / (z + 1e-16f));
}

// ---------- per-CSR-entry alpha (all H heads), written once ----------
template<int H>
__global__ __launch_bounds__(256) void edge_alpha(
    const int* __restrict__ csrc, const int* __restrict__ cdst,
    const float* __restrict__ es, const float* __restrict__ ed,
    const float2* __restrict__ mz, float* __restrict__ wse, int Etot)
{
    int i = blockIdx.x * 256 + threadIdx.x;
    if (i >= Etot) return;
    int s = csrc[i], d = cdst[i];
    float a[H];
    #pragma unroll
    for (int hh = 0; hh < H; hh++) {
        float l = es[s * H + hh] + ed[d * H + hh];
        l = l > 0.f ? l : 0.2f * l;
        float2 mzv = mz[d * H + hh];
        a[hh] = expf(l - mzv.x) * mzv.y;
    }
    if constexpr (H == 4) {
        ((float4*)wse)[i] = make_float4(a[0], a[1], a[2], a[3]);
    } else {
        wse[i] = a[0];
    }
}

// ---------- fused gather + bias + LN + ELU (+resid): one block per dst ----------
// Block holds the complete output row (T threads x 4 channels = HC).
template<int H>
__global__ __launch_bounds__(64 * H) void gat_gather_ln(
    const int* __restrict__ rowstart, const int* __restrict__ deg,
    const int* __restrict__ csrc, const float* __restrict__ wse,
    const _Float16* __restrict__ h,
    const float* __restrict__ bias, const float* __restrict__ gam,
    const float* __restrict__ bet, const float* resid,
    float* xout, _Float16* xout16)
{
    constexpr int T = 64 * H;
    constexpr int NW = H;                  // waves per block
    const int HC = T * 4;
    int d = blockIdx.x;
    int t = threadIdx.x;
    int lane = t & 63, wave = t >> 6;
    int head2 = t >> 6;                    // ch = t*4 -> head = t/64 (H=4); 0 for H=1
    int st = rowstart[d], dg = deg[d];
    const _Float16* hb = h + (size_t)t * 4;

    float a0 = 0.f, a1 = 0.f, a2 = 0.f, a3 = 0.f;
    int j = 0;
    for (; j + 2 <= dg; j += 2) {          // unroll-2: two row-loads in flight
        int s0 = csrc[st + j], s1 = csrc[st + j + 1];
        float w0 = wse[(size_t)(st + j) * H + head2];
        float w1 = wse[(size_t)(st + j + 1) * H + head2];
        f16x4 v0 = *(const f16x4*)(hb + (size_t)s0 * HC);
        f16x4 v1 = *(const f16x4*)(hb + (size_t)s1 * HC);
        a0 += w0 * (float)v0[0] + w1 * (float)v1[0];
        a1 += w0 * (float)v0[1] + w1 * (float)v1[1];
        a2 += w0 * (float)v0[2] + w1 * (float)v1[2];
        a3 += w0 * (float)v0[3] + w1 * (float)v1[3];
    }
    if (j < dg) {
        int s0 = csrc[st + j];
        float w0 = wse[(size_t)(st + j) * H + head2];
        f16x4 v0 = *(const f16x4*)(hb + (size_t)s0 * HC);
        a0 += w0 * (float)v0[0];
        a1 += w0 * (float)v0[1];
        a2 += w0 * (float)v0[2];
        a3 += w0 * (float)v0[3];
    }

    // bias
    int c0 = t * 4;
    a0 += bias[c0]; a1 += bias[c0 + 1]; a2 += bias[c0 + 2]; a3 += bias[c0 + 3];

    // layernorm over the block-owned row
    __shared__ float sm[NW];
    float sum = a0 + a1 + a2 + a3;
    #pragma unroll
    for (int o = 32; o; o >>= 1) sum += __shfl_down(sum, o);
    if (lane == 0) sm[wave] = sum;
    __syncthreads();
    float tot = 0.f;
    #pragma unroll
    for (int w2 = 0; w2 < NW; w2++) tot += sm[w2];
    float mean = tot / (float)HC;
    float d0 = a0 - mean, d1 = a1 - mean, d2 = a2 - mean, d3 = a3 - mean;
    float sq = d0 * d0 + d1 * d1 + d2 * d2 + d3 * d3;
    #pragma unroll
    for (int o = 32; o; o >>= 1) sq += __shfl_down(sq, o);
    __syncthreads();                       // sm reuse
    if (lane == 0) sm[wave] = sq;
    __syncthreads();
    tot = 0.f;
    #pragma unroll
    for (int w2 = 0; w2 < NW; w2++) tot += sm[w2];
    float rstd = rsqrtf(tot / (float)HC + 1e-5f);

    float y0 = d0 * rstd * gam[c0]     + bet[c0];
    float y1 = d1 * rstd * gam[c0 + 1] + bet[c0 + 1];
    float y2 = d2 * rstd * gam[c0 + 2] + bet[c0 + 2];
    float y3 = d3 * rstd * gam[c0 + 3] + bet[c0 + 3];
    y0 = y0 > 0.f ? y0 : (expf(y0) - 1.f);
    y1 = y1 > 0.f ? y1 : (expf(y1) - 1.f);
    y2 = y2 > 0.f ? y2 : (expf(y2) - 1.f);
    y3 = y3 > 0.f ? y3 : (expf(y3) - 1.f);
    if (resid) {
        float4 r = ((const float4*)resid)[(size_t)d * T + t];
        y0 += r.x; y1 += r.y; y2 += r.z; y3 += r.w;
    }
    ((float4*)xout)[(size_t)d * T + t] = make_float4(y0, y1, y2, y3);
    if (xout16) {
        f16x4 o;
        o[0] = (_Float16)y0; o[1] = (_Float16)y1; o[2] = (_Float16)y2; o[3] = (_Float16)y3;
        ((f16x4*)xout16)[(size_t)d * T + t] = o;
    }
}

// ---------- graph pooling: 16 nodes per block, register pre-reduce ----------
__global__ __launch_bounds__(256) void pool_kernel(
    const float* __restrict__ x3, const int* __restrict__ batch,
    float* __restrict__ ps, unsigned* __restrict__ pm, int* __restrict__ cnt, int Nn)
{
    int c = threadIdx.x;
    int n0 = blockIdx.x * 16;
    int end = n0 + 16; if (end > Nn) end = Nn;
    if (n0 >= Nn) return;
    int curg = batch[n0];
    float s = 0.f, m = -1e30f; int k = 0;
    for (int n = n0; n < end; n++) {
        int g = batch[n];
        if (g != curg) {
            atomicAdd(&ps[curg * 256 + c], s);
            atomicMax(&pm[curg * 256 + c], encf(m));
            if (c == 0) atomicAdd(&cnt[curg], k);
            s = 0.f; m = -1e30f; k = 0; curg = g;
        }
        float v = x3[(size_t)n * 256 + c];
        s += v; m = fmaxf(m, v); k++;
    }
    atomicAdd(&ps[curg * 256 + c], s);
    atomicMax(&pm[curg * 256 + c], encf(m));
    if (c == 0) atomicAdd(&cnt[curg], k);
}

// ---------- classifier: [mean|max|sum] @ W1 -> relu -> @ W2 ----------
__global__ __launch_bounds__(128) void classifier_kernel(
    const float* __restrict__ ps, const unsigned* __restrict__ pm, const int* __restrict__ cnt,
    const float* __restrict__ w1, const float* __restrict__ b1,
    const float* __restrict__ w2, const float* __restrict__ b2, float* __restrict__ out)
{
    int g = blockIdx.x;
    int tid = threadIdx.x; // 128
    __shared__ float pooled[768];
    __shared__ float red[2];
    float c = (float)cnt[g];
    if (c < 1.f) c = 1.f;
    for (int i = tid; i < 256; i += 128) {
        float s = ps[g * 256 + i];
        pooled[i] = s / c;
        pooled[256 + i] = decf(pm[g * 256 + i]);
        pooled[512 + i] = s;
    }
    __syncthreads();
    float acc = b1[tid];
    for (int k = 0; k < 768; k++) acc = fmaf(pooled[k], w1[k * 128 + tid], acc);
    acc = fmaxf(acc, 0.f);
    float v = acc * w2[tid];
    #pragma unroll
    for (int o = 32; o; o >>= 1) v += __shfl_down(v, o);
    if ((tid & 63) == 0) red[tid >> 6] = v;
    __syncthreads();
    if (tid == 0) out[g] = red[0] + red[1] + b2[0];
}

// ---------- launcher ----------
extern "C" void kernel_launch(void* const* d_in, const int* in_sizes, int n_in,
                              void* d_out, int out_size, void* d_ws, size_t ws_size,
                              hipStream_t stream)
{
    const float* x      = (const float*)d_in[0];
    const int*   ei     = (const int*)d_in[1];
    const int*   batch  = (const int*)d_in[2];
    const float* proj_w = (const float*)d_in[3];
    const float* proj_b = (const float*)d_in[4];
    const float* gat1_w = (const float*)d_in[5];
    const float* att1_s = (const float*)d_in[6];
    const float* att1_d = (const float*)d_in[7];
    const float* gat1_b = (const float*)d_in[8];
    const float* ln1_g  = (const float*)d_in[9];
    const float* ln1_b  = (const float*)d_in[10];
    const float* gat2_w = (const float*)d_in[11];
    const float* att2_s = (const float*)d_in[12];
    const float* att2_d = (const float*)d_in[13];
    const float* gat2_b = (const float*)d_in[14];
    const float* ln2_g  = (const float*)d_in[15];
    const float* ln2_b  = (const float*)d_in[16];
    const float* gat3_w = (const float*)d_in[17];
    const float* att3_s = (const float*)d_in[18];
    const float* att3_d = (const float*)d_in[19];
    const float* gat3_b = (const float*)d_in[20];
    const float* ln3_g  = (const float*)d_in[21];
    const float* ln3_b  = (const float*)d_in[22];
    const float* cls1_w = (const float*)d_in[23];
    const float* cls1_b = (const float*)d_in[24];
    const float* cls2_w = (const float*)d_in[25];
    const float* cls2_b = (const float*)d_in[26];

    int Nn = in_sizes[0] / 768;
    int E  = in_sizes[1] / 2;
    int Gg = out_size;           // 32
    int Etot = E + Nn;
    int nb  = (Nn + 255) / 256;

    // ---- workspace layout (aligned to 256 B), ~180 MB ----
    char* w = (char*)d_ws;
    size_t off = 0;
    auto alloc = [&](size_t bytes) -> char* {
        char* r = w + off;
        off += (bytes + 255) & ~(size_t)255;
        return r;
    };
    size_t NB16 = (size_t)Nn * 1024 * sizeof(_Float16);
    size_t NB32 = (size_t)Nn * 1024 * sizeof(float);
    _Float16* P = (_Float16*)alloc(NB16);     // x16 -> h1 -> h2 -> h3
    _Float16* Q = (_Float16*)alloc(NB16);     // hproj16 -> x1_16 -> x2_16
    float*  X = (float*)alloc(NB32);          // x1/x2 fp32 resid chain -> x3
    _Float16* projT = (_Float16*)alloc((size_t)768 * 768 * 2);
    _Float16* g1T   = (_Float16*)alloc((size_t)1024 * 768 * 2);
    _Float16* g2T   = (_Float16*)alloc((size_t)1024 * 1024 * 2);
    _Float16* g3T   = (_Float16*)alloc((size_t)256 * 1024 * 2);
    float*    es    = (float*)alloc((size_t)Nn * 4 * 4);
    float*    ed_   = (float*)alloc((size_t)Nn * 4 * 4);
    float2*   mz    = (float2*)alloc((size_t)Nn * 4 * 8);
    int*      deg   = (int*)alloc((size_t)Nn * 4);
    int*      incl  = (int*)alloc((size_t)Nn * 4);
    int*      rowst = (int*)alloc((size_t)Nn * 4);
    int*      curs  = (int*)alloc((size_t)Nn * 4);
    int*      bsums = (int*)alloc((size_t)nb * 4);
    int*      csrc  = (int*)alloc((size_t)Etot * 4);
    int*      cdst  = (int*)alloc((size_t)Etot * 4);
    float*    wse   = (float*)alloc((size_t)Etot * 4 * 4);
    float*    ps    = (float*)alloc((size_t)Gg * 256 * 4);
    unsigned* pm    = (unsigned*)alloc((size_t)Gg * 256 * 4);
    int*      cnt   = (int*)alloc(256);

    dim3 blk(256);

    // ---- weight transpose+convert ----
    wt_kernel<<<dim3(768 / 32, 768 / 32), blk, 0, stream>>>(proj_w, projT, 768, 768);
    wt_kernel<<<dim3(1024 / 32, 768 / 32), blk, 0, stream>>>(gat1_w, g1T, 768, 1024);
    wt_kernel<<<dim3(1024 / 32, 1024 / 32), blk, 0, stream>>>(gat2_w, g2T, 1024, 1024);
    wt_kernel<<<dim3(256 / 32, 1024 / 32), blk, 0, stream>>>(gat3_w, g3T, 1024, 256);

    // ---- x -> fp16 ----
    {
        size_t n4 = (size_t)Nn * 768 / 4;
        cvt_f16_kernel<<<dim3((unsigned)((n4 + 255) / 256)), blk, 0, stream>>>(x, P, n4);
    }

    // ---- CSR by dst ----
    csr_init<<<dim3(nb), blk, 0, stream>>>(deg, Nn);
    csr_count<<<dim3((E + 255) / 256), blk, 0, stream>>>(ei, deg, E);
    scan1<<<dim3(nb), blk, 0, stream>>>(deg, incl, bsums, Nn);
    scan2<<<dim3(1), dim3(64), 0, stream>>>(bsums, nb);
    scan3<<<dim3(nb), blk, 0, stream>>>(incl, deg, bsums, rowst, curs, Nn);
    csr_fill<<<dim3((Etot + 255) / 256), blk, 0, stream>>>(ei, curs, csrc, cdst, E, Nn);

    int mg = (Nn + 127) / 128;

    // proj: hproj16 = elu(x16 @ projW + b) -> Q
    gemm_f16<<<dim3(768 / 128, mg), blk, 0, stream>>>(P, projT, proj_b, Q, Nn, 768, 768, 1);

    auto run_gat = [&](const _Float16* xin16, const _Float16* WT, const float* as_, const float* ad_,
                       const float* gb, const float* lg, const float* lb, const float* resid,
                       _Float16* hbuf, float* xout, _Float16* xout16,
                       int K, int H, int C) {
        int HC = H * C;
        gemm_f16<<<dim3(HC / 128, mg), blk, 0, stream>>>(xin16, WT, nullptr, hbuf, Nn, K, HC, 0);
        int nw = Nn * H;
        attn_scores_kernel<<<dim3((nw + 3) / 4), blk, 0, stream>>>(hbuf, as_, ad_, es, ed_, Nn, H);
        if (H == 4) {
            seg_mz<4><<<dim3((Nn + 3) / 4), blk, 0, stream>>>(rowst, deg, csrc, es, ed_, mz, Nn);
            edge_alpha<4><<<dim3((Etot + 255) / 256), blk, 0, stream>>>(csrc, cdst, es, ed_, mz, wse, Etot);
            gat_gather_ln<4><<<dim3(Nn), dim3(256), 0, stream>>>(rowst, deg, csrc, wse, hbuf,
                                                                 gb, lg, lb, resid, xout, xout16);
        } else {
            seg_mz<1><<<dim3((Nn + 3) / 4), blk, 0, stream>>>(rowst, deg, csrc, es, ed_, mz, Nn);
            edge_alpha<1><<<dim3((Etot + 255) / 256), blk, 0, stream>>>(csrc, cdst, es, ed_, mz, wse, Etot);
            gat_gather_ln<1><<<dim3(Nn), dim3(64), 0, stream>>>(rowst, deg, csrc, wse, hbuf,
                                                                gb, lg, lb, resid, xout, xout16);
        }
    };

    // layer 1: 768 -> 4x256. A=Q(hproj) -> h1 in P; x1 -> X (fp32) + Q (fp16)
    run_gat(Q, g1T, att1_s, att1_d, gat1_b, ln1_g, ln1_b, nullptr, P, X, Q, 768, 4, 256);
    // layer 2: 1024 -> 4x256, resid x1 (X). A=Q(x1_16) -> h2 in P; x2 -> X in place + Q
    run_gat(Q, g2T, att2_s, att2_d, gat2_b, ln2_g, ln2_b, X, P, X, Q, 1024, 4, 256);
    // layer 3: 1024 -> 256 (1 head). A=Q(x2_16) -> h3 in P; x3 -> X fp32 only
    run_gat(Q, g3T, att3_s, att3_d, gat3_b, ln3_g, ln3_b, nullptr, P, X, nullptr, 1024, 1, 256);

    // pooling + classifier
    hipMemsetAsync(ps, 0, (size_t)Gg * 256 * 4, stream);
    hipMemsetAsync(pm, 0, (size_t)Gg * 256 * 4, stream);
    hipMemsetAsync(cnt, 0, (size_t)Gg * 4, stream);
    pool_kernel<<<dim3((Nn + 15) / 16), blk, 0, stream>>>(X, batch, ps, pm, cnt, Nn);
    classifier_kernel<<<dim3(Gg), dim3(128), 0, stream>>>(ps, pm, cnt, cls1_w, cls1_b, cls2_w, cls2_b, (float*)d_out);
}

// Round 8
// 807.101 us; speedup vs baseline: 15.5165x; 1.0088x over previous
//
#include <hip/hip_runtime.h>
#include <math.h>

typedef float floatx4 __attribute__((ext_vector_type(4)));
typedef _Float16 f16x8 __attribute__((ext_vector_type(8)));
typedef _Float16 f16x4 __attribute__((ext_vector_type(4)));

template<int N> struct f16vec_t;
template<> struct f16vec_t<4> { typedef f16x4 type; };
template<> struct f16vec_t<8> { typedef f16x8 type; };

// ---------- helpers ----------
__device__ __forceinline__ unsigned encf(float f) {
    unsigned u = __float_as_uint(f);
    return (u & 0x80000000u) ? ~u : (u | 0x80000000u);
}
__device__ __forceinline__ float decf(unsigned u) {
    u = (u & 0x80000000u) ? (u & 0x7FFFFFFFu) : ~u;
    return __uint_as_float(u);
}
// async global->LDS, 16 B per lane; LDS dst = wave-uniform base + lane*16
__device__ __forceinline__ void glds16(const void* g, void* l) {
    __builtin_amdgcn_global_load_lds(
        (const __attribute__((address_space(1))) unsigned int*)g,
        (__attribute__((address_space(3))) unsigned int*)l, 16, 0, 0);
}

// ---------- fp32 -> fp16 convert (vec4) ----------
__global__ __launch_bounds__(256) void cvt_f16_kernel(
    const float* __restrict__ in, _Float16* __restrict__ out, size_t n4)
{
    size_t i = (size_t)blockIdx.x * 256 + threadIdx.x;
    if (i >= n4) return;
    float4 v = ((const float4*)in)[i];
    f16x4 o;
    o[0] = (_Float16)v.x; o[1] = (_Float16)v.y; o[2] = (_Float16)v.z; o[3] = (_Float16)v.w;
    ((f16x4*)out)[i] = o;
}

// ---------- weight transpose + convert: w[K,N] fp32 -> wt[N,K] fp16 ----------
__global__ __launch_bounds__(256) void wt_kernel(
    const float* __restrict__ w, _Float16* __restrict__ wt, int K, int N)
{
    __shared__ float t[32][33];
    int bx = blockIdx.x * 32, by = blockIdx.y * 32;   // bx: n, by: k
    int tx = threadIdx.x & 31, ty = threadIdx.x >> 5; // 32x8
    for (int r = ty; r < 32; r += 8)
        t[r][tx] = w[(size_t)(by + r) * N + bx + tx];
    __syncthreads();
    for (int r = ty; r < 32; r += 8)
        wt[(size_t)(bx + r) * K + by + tx] = (_Float16)t[tx][r];
}

// ---------- fp16 MFMA GEMM, double-buffered global_load_lds staging ----------
__global__ __launch_bounds__(256) void gemm_f16(
    const _Float16* __restrict__ A, const _Float16* __restrict__ BT,
    const float* __restrict__ bias, _Float16* __restrict__ C,
    int M, int K, int N, int act)
{
    __shared__ _Float16 Al[2][128 * 32];
    __shared__ _Float16 Bl[2][128 * 32];
    int tid = threadIdx.x;
    int lane = tid & 63, wave = tid >> 6;
    int row0 = blockIdx.y * 128, col0 = blockIdx.x * 128;
    int wm = (wave >> 1) * 64, wn = (wave & 1) * 64;
    int l15 = lane & 15, quad = lane >> 4;

    int rg0 = wave * 2, rg1 = rg0 + 1;
    int srow0 = rg0 * 16 + (lane >> 2);
    int srow1 = rg1 * 16 + (lane >> 2);
    int scol = (lane & 3) * 8;
    int arow0 = row0 + srow0; if (arow0 > M - 1) arow0 = M - 1;
    int arow1 = row0 + srow1; if (arow1 > M - 1) arow1 = M - 1;
    const _Float16* gA0 = A + (size_t)arow0 * K + scol;
    const _Float16* gA1 = A + (size_t)arow1 * K + scol;
    const _Float16* gB0 = BT + (size_t)(col0 + srow0) * K + scol;
    const _Float16* gB1 = BT + (size_t)(col0 + srow1) * K + scol;

    floatx4 acc[4][4] = {};

    glds16(gA0, &Al[0][rg0 * 512]);
    glds16(gA1, &Al[0][rg1 * 512]);
    glds16(gB0, &Bl[0][rg0 * 512]);
    glds16(gB1, &Bl[0][rg1 * 512]);

    int nk = K >> 5;
    for (int it = 0; it < nk; it++) {
        int cur = it & 1, nxt = cur ^ 1;
        __syncthreads();
        if (it + 1 < nk) {
            int k1 = (it + 1) << 5;
            glds16(gA0 + k1, &Al[nxt][rg0 * 512]);
            glds16(gA1 + k1, &Al[nxt][rg1 * 512]);
            glds16(gB0 + k1, &Bl[nxt][rg0 * 512]);
            glds16(gB1 + k1, &Bl[nxt][rg1 * 512]);
        }
        f16x8 af[4], bfr[4];
        #pragma unroll
        for (int i = 0; i < 4; i++) {
            af[i]  = *(const f16x8*)&Al[cur][(wm + i * 16 + l15) * 32 + quad * 8];
            bfr[i] = *(const f16x8*)&Bl[cur][(wn + i * 16 + l15) * 32 + quad * 8];
        }
        #pragma unroll
        for (int i = 0; i < 4; i++)
            #pragma unroll
            for (int j = 0; j < 4; j++)
                acc[i][j] = __builtin_amdgcn_mfma_f32_16x16x32_f16(af[i], bfr[j], acc[i][j], 0, 0, 0);
    }

    #pragma unroll
    for (int i = 0; i < 4; i++) {
        #pragma unroll
        for (int v = 0; v < 4; v++) {
            int gr = row0 + wm + i * 16 + quad * 4 + v;
            if (gr >= M) continue;
            #pragma unroll
            for (int j = 0; j < 4; j++) {
                int gc = col0 + wn + j * 16 + l15;
                float val = acc[i][j][v];
                if (bias) val += bias[gc];
                if (act) val = val > 0.f ? val : (expf(val) - 1.f);
                C[(size_t)gr * N + gc] = (_Float16)val;
            }
        }
    }
}

// ---------- per-(node,head) attention scores from fp16 h ----------
__global__ __launch_bounds__(256) void attn_scores_kernel(
    const _Float16* __restrict__ h, const float* __restrict__ asrc, const float* __restrict__ adst,
    float* __restrict__ es, float* __restrict__ ed, int Nn, int H)
{
    int wid = (blockIdx.x * 256 + threadIdx.x) >> 6;
    int lane = threadIdx.x & 63;
    if (wid >= Nn * H) return;
    int node = wid / H, hh = wid % H;
    const _Float16* hp = h + (size_t)node * H * 256 + hh * 256 + lane * 4;
    f16x4 v = *(const f16x4*)hp;
    float ss = 0.f, sd = 0.f;
    #pragma unroll
    for (int j = 0; j < 4; j++) {
        float f = (float)v[j];
        ss = fmaf(f, asrc[hh * 256 + lane * 4 + j], ss);
        sd = fmaf(f, adst[hh * 256 + lane * 4 + j], sd);
    }
    #pragma unroll
    for (int o = 32; o; o >>= 1) { ss += __shfl_down(ss, o); sd += __shfl_down(sd, o); }
    if (lane == 0) { es[wid] = ss; ed[wid] = sd; }
}

// ---------- CSR build ----------
__global__ __launch_bounds__(256) void csr_init(int* __restrict__ deg, int Nn) {
    int i = blockIdx.x * 256 + threadIdx.x;
    if (i < Nn) deg[i] = 1;               // self-loop
}
__global__ __launch_bounds__(256) void csr_count(const int* __restrict__ ei, int* __restrict__ deg, int E) {
    int i = blockIdx.x * 256 + threadIdx.x;
    if (i < E) atomicAdd(&deg[ei[E + i]], 1);
}
__global__ __launch_bounds__(256) void scan1(const int* __restrict__ deg, int* __restrict__ incl,
                                             int* __restrict__ bsums, int Nn) {
    __shared__ int sd[256];
    int idx = blockIdx.x * 256 + threadIdx.x;
    sd[threadIdx.x] = (idx < Nn) ? deg[idx] : 0;
    __syncthreads();
    for (int o = 1; o < 256; o <<= 1) {
        int x = (threadIdx.x >= (unsigned)o) ? sd[threadIdx.x - o] : 0;
        __syncthreads();
        sd[threadIdx.x] += x;
        __syncthreads();
    }
    if (idx < Nn) incl[idx] = sd[threadIdx.x];
    if (threadIdx.x == 255) bsums[blockIdx.x] = sd[255];
}
__global__ void scan2(int* __restrict__ bsums, int nb) {
    if (blockIdx.x == 0 && threadIdx.x == 0) {
        int run = 0;
        for (int i = 0; i < nb; i++) { int v = bsums[i]; bsums[i] = run; run += v; }
    }
}
__global__ __launch_bounds__(256) void scan3(const int* __restrict__ incl, const int* __restrict__ deg,
                                             const int* __restrict__ bsums, int* __restrict__ rowstart,
                                             int* __restrict__ cursor, int Nn) {
    int idx = blockIdx.x * 256 + threadIdx.x;
    if (idx >= Nn) return;
    int rs = incl[idx] - deg[idx] + bsums[blockIdx.x];
    rowstart[idx] = rs;
    cursor[idx] = rs;
}
__global__ __launch_bounds__(256) void csr_fill(const int* __restrict__ ei, int* __restrict__ cursor,
                                                int* __restrict__ csrc, int E, int Nn) {
    int i = blockIdx.x * 256 + threadIdx.x;
    if (i >= E + Nn) return;
    int s, d;
    if (i < E) { s = ei[i]; d = ei[E + i]; } else { s = d = i - E; }
    int pos = atomicAdd(&cursor[d], 1);
    csrc[pos] = s;
}

// ---------- fused segment softmax: logits -> max -> exp/sum -> alpha in wse ----------
// One wave per dst node. Pass A: compute leaky logits (random es reads), store
// to wse, track max. Pass B: exp(l-m) stored, sum. Pass C: scale by 1/z.
template<int H>
__global__ __launch_bounds__(256) void seg_softmax(
    const int* __restrict__ rowstart, const int* __restrict__ deg,
    const int* __restrict__ csrc, const float* __restrict__ es,
    const float* __restrict__ ed, float* __restrict__ wse, int Nn)
{
    int d = (blockIdx.x * 256 + threadIdx.x) >> 6;
    int lane = threadIdx.x & 63;
    if (d >= Nn) return;
    constexpr int S = 64 / H;
    int head = lane & (H - 1);
    int slot = lane / H;
    int st = rowstart[d], dg = deg[d];
    float edv = ed[d * H + head];
    float m = -1e30f;
    for (int j = slot; j < dg; j += S) {
        float l = es[csrc[st + j] * H + head] + edv;
        l = l > 0.f ? l : 0.2f * l;
        wse[(size_t)(st + j) * H + head] = l;
        m = fmaxf(m, l);
    }
    #pragma unroll
    for (int o = H; o < 64; o <<= 1) m = fmaxf(m, __shfl_xor(m, o));
    float z = 0.f;
    for (int j = slot; j < dg; j += S) {
        float e = expf(wse[(size_t)(st + j) * H + head] - m);
        wse[(size_t)(st + j) * H + head] = e;
        z += e;
    }
    #pragma unroll
    for (int o = H; o < 64; o <<= 1) z += __shfl_xor(z, o);
    float rz = 1.f / (z + 1e-16f);
    for (int j = slot; j < dg; j += S)
        wse[(size_t)(st + j) * H + head] *= rz;
}

// ---------- fused gather + bias + LN + ELU (+resid): one block per dst ----------
// H=4: 128 threads x 8 ch (f16x8 16B loads); H=1: 64 threads x 4 ch.
template<int H>
__global__ __launch_bounds__(H == 4 ? 128 : 64) void gat_gather_ln(
    const int* __restrict__ rowstart, const int* __restrict__ deg,
    const int* __restrict__ csrc, const float* __restrict__ wse,
    const _Float16* __restrict__ h,
    const float* __restrict__ bias, const float* __restrict__ gam,
    const float* __restrict__ bet, const float* resid,
    float* xout, _Float16* xout16)
{
    constexpr int T = (H == 4) ? 128 : 64;
    constexpr int CPT = (H == 4) ? 8 : 4;      // channels per thread
    constexpr int NW = T / 64;
    constexpr int HC = H * 256;
    typedef typename f16vec_t<CPT>::type hvec;
    int d = blockIdx.x;
    int t = threadIdx.x;
    int lane = t & 63, wave = t >> 6;
    int ch0 = t * CPT;
    int head2 = ch0 >> 8;
    int st = rowstart[d], dg = deg[d];
    const _Float16* hb = h + ch0;

    float acc[CPT];
    #pragma unroll
    for (int k = 0; k < CPT; k++) acc[k] = 0.f;

    int j = 0;
    for (; j + 2 <= dg; j += 2) {              // two 16B loads in flight
        int s0 = csrc[st + j], s1 = csrc[st + j + 1];
        float w0 = wse[(size_t)(st + j) * H + head2];
        float w1 = wse[(size_t)(st + j + 1) * H + head2];
        hvec v0 = *(const hvec*)(hb + (size_t)s0 * HC);
        hvec v1 = *(const hvec*)(hb + (size_t)s1 * HC);
        #pragma unroll
        for (int k = 0; k < CPT; k++)
            acc[k] += w0 * (float)v0[k] + w1 * (float)v1[k];
    }
    if (j < dg) {
        int s0 = csrc[st + j];
        float w0 = wse[(size_t)(st + j) * H + head2];
        hvec v0 = *(const hvec*)(hb + (size_t)s0 * HC);
        #pragma unroll
        for (int k = 0; k < CPT; k++) acc[k] += w0 * (float)v0[k];
    }

    #pragma unroll
    for (int k = 0; k < CPT; k++) acc[k] += bias[ch0 + k];

    // layernorm over the block-owned row
    __shared__ float sm[NW > 1 ? NW : 1];
    float sum = 0.f;
    #pragma unroll
    for (int k = 0; k < CPT; k++) sum += acc[k];
    #pragma unroll
    for (int o = 32; o; o >>= 1) sum += __shfl_down(sum, o);
    float tot;
    if (NW > 1) {
        if (lane == 0) sm[wave] = sum;
        __syncthreads();
        tot = 0.f;
        #pragma unroll
        for (int w2 = 0; w2 < NW; w2++) tot += sm[w2];
    } else {
        tot = __shfl(sum, 0);
    }
    float mean = tot / (float)HC;
    float sq = 0.f;
    #pragma unroll
    for (int k = 0; k < CPT; k++) { float dd = acc[k] - mean; sq = fmaf(dd, dd, sq); }
    #pragma unroll
    for (int o = 32; o; o >>= 1) sq += __shfl_down(sq, o);
    if (NW > 1) {
        __syncthreads();
        if (lane == 0) sm[wave] = sq;
        __syncthreads();
        tot = 0.f;
        #pragma unroll
        for (int w2 = 0; w2 < NW; w2++) tot += sm[w2];
    } else {
        tot = __shfl(sq, 0);
    }
    float rstd = rsqrtf(tot / (float)HC + 1e-5f);

    float y[CPT];
    #pragma unroll
    for (int k = 0; k < CPT; k++) {
        float v = (acc[k] - mean) * rstd * gam[ch0 + k] + bet[ch0 + k];
        y[k] = v > 0.f ? v : (expf(v) - 1.f);
    }
    if (resid) {
        #pragma unroll
        for (int q = 0; q < CPT / 4; q++) {
            float4 r = ((const float4*)resid)[(size_t)d * (HC / 4) + t * (CPT / 4) + q];
            y[q * 4 + 0] += r.x; y[q * 4 + 1] += r.y; y[q * 4 + 2] += r.z; y[q * 4 + 3] += r.w;
        }
    }
    #pragma unroll
    for (int q = 0; q < CPT / 4; q++)
        ((float4*)xout)[(size_t)d * (HC / 4) + t * (CPT / 4) + q] =
            make_float4(y[q * 4 + 0], y[q * 4 + 1], y[q * 4 + 2], y[q * 4 + 3]);
    if (xout16) {
        hvec o;
        #pragma unroll
        for (int k = 0; k < CPT; k++) o[k] = (_Float16)y[k];
        *(hvec*)(xout16 + (size_t)d * HC + ch0) = o;
    }
}

// ---------- graph pooling: 16 nodes per block, register pre-reduce ----------
__global__ __launch_bounds__(256) void pool_kernel(
    const float* __restrict__ x3, const int* __restrict__ batch,
    float* __restrict__ ps, unsigned* __restrict__ pm, int* __restrict__ cnt, int Nn)
{
    int c = threadIdx.x;
    int n0 = blockIdx.x * 16;
    int end = n0 + 16; if (end > Nn) end = Nn;
    if (n0 >= Nn) return;
    int curg = batch[n0];
    float s = 0.f, m = -1e30f; int k = 0;
    for (int n = n0; n < end; n++) {
        int g = batch[n];
        if (g != curg) {
            atomicAdd(&ps[curg * 256 + c], s);
            atomicMax(&pm[curg * 256 + c], encf(m));
            if (c == 0) atomicAdd(&cnt[curg], k);
            s = 0.f; m = -1e30f; k = 0; curg = g;
        }
        float v = x3[(size_t)n * 256 + c];
        s += v; m = fmaxf(m, v); k++;
    }
    atomicAdd(&ps[curg * 256 + c], s);
    atomicMax(&pm[curg * 256 + c], encf(m));
    if (c == 0) atomicAdd(&cnt[curg], k);
}

// ---------- classifier: [mean|max|sum] @ W1 -> relu -> @ W2 ----------
__global__ __launch_bounds__(128) void classifier_kernel(
    const float* __restrict__ ps, const unsigned* __restrict__ pm, const int* __restrict__ cnt,
    const float* __restrict__ w1, const float* __restrict__ b1,
    const float* __restrict__ w2, const float* __restrict__ b2, float* __restrict__ out)
{
    int g = blockIdx.x;
    int tid = threadIdx.x; // 128
    __shared__ float pooled[768];
    __shared__ float red[2];
    float c = (float)cnt[g];
    if (c < 1.f) c = 1.f;
    for (int i = tid; i < 256; i += 128) {
        float s = ps[g * 256 + i];
        pooled[i] = s / c;
        pooled[256 + i] = decf(pm[g * 256 + i]);
        pooled[512 + i] = s;
    }
    __syncthreads();
    float acc = b1[tid];
    for (int k = 0; k < 768; k++) acc = fmaf(pooled[k], w1[k * 128 + tid], acc);
    acc = fmaxf(acc, 0.f);
    float v = acc * w2[tid];
    #pragma unroll
    for (int o = 32; o; o >>= 1) v += __shfl_down(v, o);
    if ((tid & 63) == 0) red[tid >> 6] = v;
    __syncthreads();
    if (tid == 0) out[g] = red[0] + red[1] + b2[0];
}

// ---------- launcher ----------
extern "C" void kernel_launch(void* const* d_in, const int* in_sizes, int n_in,
                              void* d_out, int out_size, void* d_ws, size_t ws_size,
                              hipStream_t stream)
{
    const float* x      = (const float*)d_in[0];
    const int*   ei     = (const int*)d_in[1];
    const int*   batch  = (const int*)d_in[2];
    const float* proj_w = (const float*)d_in[3];
    const float* proj_b = (const float*)d_in[4];
    const float* gat1_w = (const float*)d_in[5];
    const float* att1_s = (const float*)d_in[6];
    const float* att1_d = (const float*)d_in[7];
    const float* gat1_b = (const float*)d_in[8];
    const float* ln1_g  = (const float*)d_in[9];
    const float* ln1_b  = (const float*)d_in[10];
    const float* gat2_w = (const float*)d_in[11];
    const float* att2_s = (const float*)d_in[12];
    const float* att2_d = (const float*)d_in[13];
    const float* gat2_b = (const float*)d_in[14];
    const float* ln2_g  = (const float*)d_in[15];
    const float* ln2_b  = (const float*)d_in[16];
    const float* gat3_w = (const float*)d_in[17];
    const float* att3_s = (const float*)d_in[18];
    const float* att3_d = (const float*)d_in[19];
    const float* gat3_b = (const float*)d_in[20];
    const float* ln3_g  = (const float*)d_in[21];
    const float* ln3_b  = (const float*)d_in[22];
    const float* cls1_w = (const float*)d_in[23];
    const float* cls1_b = (const float*)d_in[24];
    const float* cls2_w = (const float*)d_in[25];
    const float* cls2_b = (const float*)d_in[26];

    int Nn = in_sizes[0] / 768;
    int E  = in_sizes[1] / 2;
    int Gg = out_size;           // 32
    int Etot = E + Nn;
    int nb  = (Nn + 255) / 256;

    // ---- workspace layout (aligned to 256 B) ----
    char* w = (char*)d_ws;
    size_t off = 0;
    auto alloc = [&](size_t bytes) -> char* {
        char* r = w + off;
        off += (bytes + 255) & ~(size_t)255;
        return r;
    };
    size_t NB16 = (size_t)Nn * 1024 * sizeof(_Float16);
    size_t NB32 = (size_t)Nn * 1024 * sizeof(float);
    _Float16* P = (_Float16*)alloc(NB16);     // x16 -> h1 -> h2 -> h3
    _Float16* Q = (_Float16*)alloc(NB16);     // hproj16 -> x1_16 -> x2_16
    float*  X = (float*)alloc(NB32);          // x1/x2 fp32 resid chain -> x3
    _Float16* projT = (_Float16*)alloc((size_t)768 * 768 * 2);
    _Float16* g1T   = (_Float16*)alloc((size_t)1024 * 768 * 2);
    _Float16* g2T   = (_Float16*)alloc((size_t)1024 * 1024 * 2);
    _Float16* g3T   = (_Float16*)alloc((size_t)256 * 1024 * 2);
    float*    es    = (float*)alloc((size_t)Nn * 4 * 4);
    float*    ed_   = (float*)alloc((size_t)Nn * 4 * 4);
    int*      deg   = (int*)alloc((size_t)Nn * 4);
    int*      incl  = (int*)alloc((size_t)Nn * 4);
    int*      rowst = (int*)alloc((size_t)Nn * 4);
    int*      curs  = (int*)alloc((size_t)Nn * 4);
    int*      bsums = (int*)alloc((size_t)nb * 4);
    int*      csrc  = (int*)alloc((size_t)Etot * 4);
    float*    wse   = (float*)alloc((size_t)Etot * 4 * 4);
    float*    ps    = (float*)alloc((size_t)Gg * 256 * 4);
    unsigned* pm    = (unsigned*)alloc((size_t)Gg * 256 * 4);
    int*      cnt   = (int*)alloc(256);

    dim3 blk(256);

    // ---- weight transpose+convert ----
    wt_kernel<<<dim3(768 / 32, 768 / 32), blk, 0, stream>>>(proj_w, projT, 768, 768);
    wt_kernel<<<dim3(1024 / 32, 768 / 32), blk, 0, stream>>>(gat1_w, g1T, 768, 1024);
    wt_kernel<<<dim3(1024 / 32, 1024 / 32), blk, 0, stream>>>(gat2_w, g2T, 1024, 1024);
    wt_kernel<<<dim3(256 / 32, 1024 / 32), blk, 0, stream>>>(gat3_w, g3T, 1024, 256);

    // ---- x -> fp16 ----
    {
        size_t n4 = (size_t)Nn * 768 / 4;
        cvt_f16_kernel<<<dim3((unsigned)((n4 + 255) / 256)), blk, 0, stream>>>(x, P, n4);
    }

    // ---- CSR by dst ----
    csr_init<<<dim3(nb), blk, 0, stream>>>(deg, Nn);
    csr_count<<<dim3((E + 255) / 256), blk, 0, stream>>>(ei, deg, E);
    scan1<<<dim3(nb), blk, 0, stream>>>(deg, incl, bsums, Nn);
    scan2<<<dim3(1), dim3(64), 0, stream>>>(bsums, nb);
    scan3<<<dim3(nb), blk, 0, stream>>>(incl, deg, bsums, rowst, curs, Nn);
    csr_fill<<<dim3((Etot + 255) / 256), blk, 0, stream>>>(ei, curs, csrc, E, Nn);

    int mg = (Nn + 127) / 128;

    // proj: hproj16 = elu(x16 @ projW + b) -> Q
    gemm_f16<<<dim3(768 / 128, mg), blk, 0, stream>>>(P, projT, proj_b, Q, Nn, 768, 768, 1);

    auto run_gat = [&](const _Float16* xin16, const _Float16* WT, const float* as_, const float* ad_,
                       const float* gb, const float* lg, const float* lb, const float* resid,
                       _Float16* hbuf, float* xout, _Float16* xout16,
                       int K, int H, int C) {
        int HC = H * C;
        gemm_f16<<<dim3(HC / 128, mg), blk, 0, stream>>>(xin16, WT, nullptr, hbuf, Nn, K, HC, 0);
        int nw = Nn * H;
        attn_scores_kernel<<<dim3((nw + 3) / 4), blk, 0, stream>>>(hbuf, as_, ad_, es, ed_, Nn, H);
        if (H == 4) {
            seg_softmax<4><<<dim3((Nn + 3) / 4), blk, 0, stream>>>(rowst, deg, csrc, es, ed_, wse, Nn);
            gat_gather_ln<4><<<dim3(Nn), dim3(128), 0, stream>>>(rowst, deg, csrc, wse, hbuf,
                                                                 gb, lg, lb, resid, xout, xout16);
        } else {
            seg_softmax<1><<<dim3((Nn + 3) / 4), blk, 0, stream>>>(rowst, deg, csrc, es, ed_, wse, Nn);
            gat_gather_ln<1><<<dim3(Nn), dim3(64), 0, stream>>>(rowst, deg, csrc, wse, hbuf,
                                                                gb, lg, lb, resid, xout, xout16);
        }
    };

    // layer 1: 768 -> 4x256. A=Q(hproj) -> h1 in P; x1 -> X (fp32) + Q (fp16)
    run_gat(Q, g1T, att1_s, att1_d, gat1_b, ln1_g, ln1_b, nullptr, P, X, Q, 768, 4, 256);
    // layer 2: 1024 -> 4x256, resid x1 (X). A=Q(x1_16) -> h2 in P; x2 -> X in place + Q
    run_gat(Q, g2T, att2_s, att2_d, gat2_b, ln2_g, ln2_b, X, P, X, Q, 1024, 4, 256);
    // layer 3: 1024 -> 256 (1 head). A=Q(x2_16) -> h3 in P; x3 -> X fp32 only
    run_gat(Q, g3T, att3_s, att3_d, gat3_b, ln3_g, ln3_b, nullptr, P, X, nullptr, 1024, 1, 256);

    // pooling + classifier
    hipMemsetAsync(ps, 0, (size_t)Gg * 256 * 4, stream);
    hipMemsetAsync(pm, 0, (size_t)Gg * 256 * 4, stream);
    hipMemsetAsync(cnt, 0, (size_t)Gg * 4, stream);
    pool_kernel<<<dim3((Nn + 15) / 16), blk, 0, stream>>>(X, batch, ps, pm, cnt, Nn);
    classifier_kernel<<<dim3(Gg), dim3(128), 0, stream>>>(ps, pm, cnt, cls1_w, cls1_b, cls2_w, cls2_b, (float*)d_out);
}